// Round 7
// baseline (614.689 us; speedup 1.0000x reference)
//
#include <hip/hip_runtime.h>
#include <hip/hip_bf16.h>

#define NZv 1
#define NYv 400
#define NXv 352
#define Bv 4
#define CANVASv (Bv * NZv * NYv * NXv) /* 563200 = 550 * 1024 */
#define EPSF 0.001f
#define VXF 0.2f
#define VYF 0.2f
#define VZF 4.0f
#define XOFFv 0.1f
#define YOFFv -39.9f
#define ZOFFv -1.0f
#define NPART 512  /* mom1 grid / partial count */

typedef __attribute__((ext_vector_type(8))) short bf16x8;
typedef __attribute__((ext_vector_type(4))) float f32x4;

__device__ __forceinline__ short f2bf(float f) {
    union { __hip_bfloat16 h; short s; } u;
    u.h = __float2bfloat16(f);
    return u.s;
}
__device__ __forceinline__ float bf2f(short s) {
    return __uint_as_float(((unsigned int)(unsigned short)s) << 16);
}
__device__ __forceinline__ unsigned int pk(float a, float b) {
    return (unsigned int)(unsigned short)f2bf(a) | ((unsigned int)(unsigned short)f2bf(b) << 16);
}

// compile-time index tables for the 105 upper-triangle moments (a<=b, a-major)
struct MomTab { signed char a[105]; signed char b[105]; };
constexpr MomTab make_momtab() {
    MomTab m{};
    int idx = 0;
    for (int a = 0; a < 14; ++a)
        for (int b = a; b < 14; ++b) { m.a[idx] = (signed char)a; m.b[idx] = (signed char)b; ++idx; }
    return m;
}
constexpr MomTab MT = make_momtab();

// ---------------- scatter pass 1: count + coord sums ----------------
__global__ void k_scatter1(const float4* __restrict__ feat, const int4* __restrict__ coors,
                           int* __restrict__ vidx, float* __restrict__ counts,
                           float* __restrict__ sumc, int n)
{
    int i = blockIdx.x * blockDim.x + threadIdx.x;
    if (i >= n) return;
    int4 c = coors[i];
    int v = ((c.x * NZv + c.y) * NYv + c.z) * NXv + c.w;
    vidx[i] = v;
    float4 f = feat[i];
    atomicAdd(&counts[v], 1.0f);
    atomicAdd(&sumc[3 * v + 0], f.x);
    atomicAdd(&sumc[3 * v + 1], f.y);
    atomicAdd(&sumc[3 * v + 2], f.z);
}

// ---------------- scatter pass 2: mean-dist sums ----------------
__global__ void k_scatter2(const float4* __restrict__ feat, const int* __restrict__ vidx,
                           const float* __restrict__ counts, const float* __restrict__ sumc,
                           float* __restrict__ spd, int n)
{
    int i = blockIdx.x * blockDim.x + threadIdx.x;
    if (i >= n) return;
    int v = vidx[i];
    float safe = fmaxf(counts[v], 1.0f);
    float inv = 1.0f / safe;
    float4 f = feat[i];
    float dx = f.x - sumc[3 * v + 0] * inv;
    float dy = f.y - sumc[3 * v + 1] * inv;
    float dz = f.z - sumc[3 * v + 2] * inv;
    atomicAdd(&spd[v], sqrtf(dx * dx + dy * dy + dz * dz));
}

// ---------------- prex: build x bf16[n][16] (streaming) ----------------
__global__ __launch_bounds__(256) void k_prex(const float4* __restrict__ feat,
                       const int4* __restrict__ coors,
                       const int* __restrict__ vidx, const float* __restrict__ counts,
                       const float* __restrict__ sumc, const float* __restrict__ spd,
                       unsigned int* __restrict__ x, int n)
{
    int t = threadIdx.x;
    int stride = gridDim.x * blockDim.x;
    for (int i = blockIdx.x * blockDim.x + t; i < n; i += stride) {
        float4 f = feat[i];
        int4 c = coors[i];
        int v = vidx[i];
        float safe = fmaxf(counts[v], 1.0f);
        float inv = 1.0f / safe;
        float vals[13];
        vals[0] = f.x; vals[1] = f.y; vals[2] = f.z; vals[3] = f.w;
        vals[4] = safe / 0.16f;
        vals[5] = spd[v] * inv;
        vals[6] = f.x - sumc[3 * v + 0] * inv;
        vals[7] = f.y - sumc[3 * v + 1] * inv;
        vals[8] = f.z - sumc[3 * v + 2] * inv;
        vals[9]  = f.x - ((float)c.w * VXF + XOFFv);
        vals[10] = f.y - ((float)c.z * VYF + YOFFv);
        vals[11] = f.z - ((float)c.y * VZF + ZOFFv);
        vals[12] = sqrtf(f.x * f.x + f.y * f.y + f.z * f.z);
        unsigned int row[8];
#pragma unroll
        for (int q = 0; q < 6; ++q) row[q] = pk(vals[2 * q], vals[2 * q + 1]);
        row[6] = pk(vals[12], 0.f);
        row[7] = 0u;
        uint4* dst = (uint4*)(x + (size_t)i * 8);
        dst[0] = make_uint4(row[0], row[1], row[2], row[3]);
        dst[1] = make_uint4(row[4], row[5], row[6], row[7]);
    }
}

// ---------------- mom: 14x14 moments from bf16 x rows, all-static indexing ----------------
__global__ __launch_bounds__(256, 1) void k_mom(const uint4* __restrict__ x4,
                                                double* __restrict__ md0, int n)
{
    float acc[105];
#pragma unroll
    for (int e = 0; e < 105; ++e) acc[e] = 0.f;
    int t = threadIdx.x;
    int stride = gridDim.x * blockDim.x;
    for (int i = blockIdx.x * blockDim.x + t; i < n; i += stride) {
        uint4 r0 = x4[2 * (size_t)i];
        uint4 r1 = x4[2 * (size_t)i + 1];
        unsigned int rw[7] = {r0.x, r0.y, r0.z, r0.w, r1.x, r1.y, r1.z};
        float vals[14];
#pragma unroll
        for (int k = 0; k < 13; ++k)
            vals[k] = bf2f((short)((k & 1) ? (rw[k >> 1] >> 16) : (rw[k >> 1] & 0xFFFF)));
        vals[13] = 1.0f;
#pragma unroll
        for (int e = 0; e < 105; ++e)
            acc[e] = fmaf(vals[MT.a[e]], vals[MT.b[e]], acc[e]);
    }
    __shared__ float wacc[4][105];
    int lane = t & 63, wid = t >> 6;
#pragma unroll
    for (int e = 0; e < 105; ++e) {
        float v = acc[e];
        v += __shfl_xor(v, 1);
        v += __shfl_xor(v, 2);
        v += __shfl_xor(v, 4);
        v += __shfl_xor(v, 8);
        v += __shfl_xor(v, 16);
        v += __shfl_xor(v, 32);
        if (lane == 0) wacc[wid][e] = v;
    }
    __syncthreads();
    if (t < 105) {
        double s = (double)wacc[0][t] + (double)wacc[1][t] + (double)wacc[2][t] + (double)wacc[3][t];
        atomicAdd(&md0[t], s);
    }
}

__device__ __forceinline__ int idx14(int a, int b) { // a<=b
    return a * 14 - a * (a - 1) / 2 + (b - a);
}

// ---------------- fin0: BN0 scale/shift from moments ----------------
__global__ void k_fin0(const double* __restrict__ md0, const float* __restrict__ W0,
                       const float* __restrict__ g0, const float* __restrict__ b0,
                       float* __restrict__ sc0, float* __restrict__ sh0, int n)
{
    __shared__ double mom[105];
    int t = threadIdx.x;
    for (int e = t; e < 105; e += 64) mom[e] = md0[e];
    __syncthreads();
    double nn = (double)n;
    double mu[13];
#pragma unroll
    for (int j = 0; j < 13; ++j) mu[j] = mom[idx14(j, 13)] / nn;
    double wc[13];
#pragma unroll
    for (int j = 0; j < 13; ++j) wc[j] = (double)W0[j * 64 + t];
    double meanc = 0.0, var = 0.0;
#pragma unroll
    for (int j = 0; j < 13; ++j) {
        meanc += mu[j] * wc[j];
        for (int k = 0; k < 13; ++k) {
            int a = j < k ? j : k, b = j < k ? k : j;
            double cov = mom[idx14(a, b)] / nn - mu[j] * mu[k];
            var += cov * wc[j] * wc[k];
        }
    }
    float scale = g0[t] * rsqrtf((float)var + EPSF);
    sc0[t] = scale;
    sh0[t] = b0[t] - (float)meanc * scale;
}

// ---------------- scanA ----------------
__global__ __launch_bounds__(1024) void k_scanA(const float* __restrict__ counts,
                                                int* __restrict__ starts, int* __restrict__ bsum)
{
    __shared__ int sdata[1024];
    int t = threadIdx.x;
    int v = blockIdx.x * 1024 + t;
    int c = (int)counts[v];
    sdata[t] = c;
    __syncthreads();
#pragma unroll
    for (int off = 1; off < 1024; off <<= 1) {
        int val = (t >= off) ? sdata[t - off] : 0;
        __syncthreads();
        sdata[t] += val;
        __syncthreads();
    }
    starts[v] = sdata[t] - c; // exclusive
    if (t == 1023) bsum[blockIdx.x] = sdata[t];
}

// ---------------- scanB ----------------
__global__ __launch_bounds__(1024) void k_scanB(int* __restrict__ bsum, int* __restrict__ boff)
{
    __shared__ int sdata[1024];
    int t = threadIdx.x;
    int c = (t < 550) ? bsum[t] : 0;
    sdata[t] = c;
    __syncthreads();
#pragma unroll
    for (int off = 1; off < 1024; off <<= 1) {
        int val = (t >= off) ? sdata[t - off] : 0;
        __syncthreads();
        sdata[t] += val;
        __syncthreads();
    }
    if (t < 550) boff[t] = sdata[t] - c;
}

// ---------------- scanC ----------------
__global__ __launch_bounds__(1024) void k_scanC(int* __restrict__ starts, const int* __restrict__ boff)
{
    int v = blockIdx.x * 1024 + threadIdx.x;
    starts[v] += boff[blockIdx.x];
}

// ---------------- perm (starts becomes INCLUSIVE prefix after this) ----------------
__global__ void k_perm(const int* __restrict__ vidx, int* __restrict__ starts,
                       int* __restrict__ perm, int n)
{
    int i = blockIdx.x * blockDim.x + threadIdx.x;
    if (i >= n) return;
    int pos = atomicAdd(&starts[vidx[i]], 1);
    perm[pos] = i;
}

// ---------------- vmaxv: per-voxel max of p0 + per-point p0 write (bf16) ----------------
__global__ __launch_bounds__(256) void k_vmaxv(const unsigned int* __restrict__ x,
    const float* __restrict__ W0, const float* __restrict__ sc0, const float* __restrict__ sh0,
    const int* __restrict__ startsPost, const int* __restrict__ perm,
    unsigned int* __restrict__ p0, unsigned int* __restrict__ vmaxb, int nvox)
{
    int t = threadIdx.x, lane = t & 63, wid = t >> 6;
    int v = blockIdx.x * 4 + wid;
    if (v >= nvox) return;
    int end = startsPost[v];
    int begin = (v > 0) ? startsPost[v - 1] : 0;
    if (begin == end) return;
    float wcol[13];
#pragma unroll
    for (int k = 0; k < 13; ++k) wcol[k] = W0[k * 64 + lane];
    float sc = sc0[lane], sh = sh0[lane];
    float m = 0.f;
    for (int j = begin; j < end; ++j) {
        int i = perm[j];
        const uint4* xr = (const uint4*)(x + (size_t)i * 8);
        uint4 r0 = xr[0], r1 = xr[1];
        unsigned int rw[8] = {r0.x, r0.y, r0.z, r0.w, r1.x, r1.y, r1.z, r1.w};
        float acc = 0.f;
#pragma unroll
        for (int k = 0; k < 13; ++k) {
            float xv = bf2f((short)((k & 1) ? (rw[k >> 1] >> 16) : (rw[k >> 1] & 0xFFFF)));
            acc = fmaf(xv, wcol[k], acc);
        }
        float pv = fmaxf(fmaf(acc, sc, sh), 0.f);
        float pn = __shfl_xor(pv, 1);
        if ((lane & 1) == 0)
            p0[(size_t)i * 32 + (lane >> 1)] = pk(pv, pn);
        m = fmaxf(m, pv);
    }
    float mn = __shfl_xor(m, 1);
    if ((lane & 1) == 0)
        vmaxb[(size_t)v * 32 + (lane >> 1)] = pk(m, mn);
}

// ---------------- mom1: M1 = X1^T X1 via MFMA over transposed LDS tiles ----------------
__global__ __launch_bounds__(512) void k_mom1(const unsigned int* __restrict__ p0,
    const unsigned int* __restrict__ vmaxb, const int* __restrict__ vidx,
    float* __restrict__ partials, double* __restrict__ s1d, int n, int ntiles)
{
    __shared__ __align__(16) char sxT[128 * 256]; // [ch][pt] bf16, swizzled
    __shared__ float s1b[128];
    int t = threadIdx.x, lane = t & 63, w = t >> 6;
    int pl = lane & 15, qd = lane >> 4;
    int ptp = t >> 3, s = t & 7;       // pt-pair 0..63, ch-group 0..7 (16 ch each)
    if (t < 128) s1b[t] = 0.f;

    f32x4 acc[8];
#pragma unroll
    for (int cb = 0; cb < 8; ++cb) acc[cb] = (f32x4){0.f, 0.f, 0.f, 0.f};
    float s1loc[16];
#pragma unroll
    for (int q = 0; q < 16; ++q) s1loc[q] = 0.f;

    unsigned int szr = (unsigned int)(pl & 7) << 4;
    int r0 = w * 16;
    __syncthreads();

    for (int tile = blockIdx.x; tile < ntiles; tile += gridDim.x) {
        int base = tile * 128;
        // ---- stage transposed: sxT[ch][pt] for ch = s*16..+15, pt = 2*ptp, 2*ptp+1 ----
        {
            int i0 = base + 2 * ptp, i1 = i0 + 1;
            uint4 a0, a1, b0, b1;
            if (i0 < n) {
                const uint4* srcA = (s < 4)
                    ? (const uint4*)(p0 + (size_t)i0 * 32 + s * 8)
                    : (const uint4*)(vmaxb + (size_t)vidx[i0] * 32 + (s - 4) * 8);
                a0 = srcA[0]; a1 = srcA[1];
            } else a0 = a1 = make_uint4(0u, 0u, 0u, 0u);
            if (i1 < n) {
                const uint4* srcB = (s < 4)
                    ? (const uint4*)(p0 + (size_t)i1 * 32 + s * 8)
                    : (const uint4*)(vmaxb + (size_t)vidx[i1] * 32 + (s - 4) * 8);
                b0 = srcB[0]; b1 = srcB[1];
            } else b0 = b1 = make_uint4(0u, 0u, 0u, 0u);
            unsigned int wa[8] = {a0.x, a0.y, a0.z, a0.w, a1.x, a1.y, a1.z, a1.w};
            unsigned int wb[8] = {b0.x, b0.y, b0.z, b0.w, b1.x, b1.y, b1.z, b1.w};
#pragma unroll
            for (int m = 0; m < 8; ++m) {
                int ch0 = s * 16 + 2 * m;
                unsigned int lo = (wa[m] & 0xFFFFu) | (wb[m] << 16);
                unsigned int hi = (wa[m] >> 16) | (wb[m] & 0xFFFF0000u);
                *(unsigned int*)(sxT + ch0 * 256 + ((ptp * 4) ^ ((ch0 & 7) << 4))) = lo;
                int ch1 = ch0 + 1;
                *(unsigned int*)(sxT + ch1 * 256 + ((ptp * 4) ^ ((ch1 & 7) << 4))) = hi;
                s1loc[2 * m]     += bf2f((short)(wa[m] & 0xFFFF)) + bf2f((short)(wb[m] & 0xFFFF));
                s1loc[2 * m + 1] += bf2f((short)(wa[m] >> 16)) + bf2f((short)(wb[m] >> 16));
            }
        }
        __syncthreads();
        // ---- MFMA: acc[cb] += A[r0-block] * B[cb-block], contract over pt ----
#pragma unroll
        for (int kc = 0; kc < 4; ++kc) {
            int ko2 = kc * 64 + qd * 16;
            bf16x8 a = *(bf16x8*)(sxT + (r0 + pl) * 256 + (ko2 ^ szr));
#pragma unroll
            for (int cb = 0; cb < 8; ++cb) {
                int rb = cb * 16 + pl;
                bf16x8 b = *(bf16x8*)(sxT + rb * 256 + (ko2 ^ szr));
                acc[cb] = __builtin_amdgcn_mfma_f32_16x16x32_bf16(a, b, acc[cb], 0, 0, 0);
            }
        }
        __syncthreads();
    }
    // ---- write partials: D[ch1 = r0 + qd*4 + jj][ch2 = cb*16 + pl] ----
    size_t pb = (size_t)blockIdx.x * 16384;
#pragma unroll
    for (int cb = 0; cb < 8; ++cb)
#pragma unroll
        for (int jj = 0; jj < 4; ++jj)
            partials[pb + (size_t)(r0 + qd * 4 + jj) * 128 + cb * 16 + pl] = acc[cb][jj];
    // ---- column sums ----
#pragma unroll
    for (int q = 0; q < 16; ++q)
        atomicAdd(&s1b[s * 16 + q], s1loc[q]);
    __syncthreads();
    if (t < 128) atomicAdd(&s1d[t], (double)s1b[t]);
}

// ---------------- reduce M1 partials ----------------
__global__ void k_redM1(const float* __restrict__ partials, float* __restrict__ M1)
{
    int e = blockIdx.x * 256 + threadIdx.x;
    float s = 0.f;
#pragma unroll 8
    for (int r = 0; r < NPART; ++r) s += partials[(size_t)r * 16384 + e];
    M1[e] = s;
}

// ---------------- fin1q: BN1 scale/shift via quadratic form ----------------
__global__ __launch_bounds__(256) void k_fin1q(const float* __restrict__ M1, const double* __restrict__ s1d,
    const float* __restrict__ W1, const float* __restrict__ g1, const float* __restrict__ b1,
    float* __restrict__ sc1, float* __restrict__ sh1, int n)
{
    __shared__ float mu[128];
    int t = threadIdx.x, lane = t & 63, wv = t >> 6;
    float invn = 1.f / (float)n;
    if (t < 128) mu[t] = (float)s1d[t] * invn;
    __syncthreads();
    int c = blockIdx.x * 4 + wv;
    float q = 0.f;
    for (int it = 0; it < 256; ++it) {
        int e = it * 64 + lane;
        int j = e >> 7, k = e & 127;
        float cv = M1[e] * invn - mu[j] * mu[k];
        q = fmaf(cv * W1[j * 128 + c], W1[k * 128 + c], q);
    }
    float m = fmaf(mu[lane], W1[lane * 128 + c], mu[lane + 64] * W1[(lane + 64) * 128 + c]);
    for (int msk = 1; msk < 64; msk <<= 1) { q += __shfl_xor(q, msk); m += __shfl_xor(m, msk); }
    if (lane == 0) {
        float scale = g1[c] * rsqrtf(q + EPSF);
        sc1[c] = scale;
        sh1[c] = b1[c] - m * scale;
    }
}

// ---------------- fused3: X1@W1 -> BN+ReLU (reg) -> [.|fsp]@Ws + bs -> ReLU -> out ----------------
#define F3_SW1 0
#define F3_SWS 32768
#define F3_SX  (32768 + 49152)
#define F3_SCL (32768 + 49152 + 49152)
#define F3_LDS (F3_SCL + 1536)

__global__ __launch_bounds__(512) void k_fused3(const unsigned int* __restrict__ p0,
    const unsigned int* __restrict__ vmaxb, const int* __restrict__ vidx,
    const unsigned int* __restrict__ x,
    const float* __restrict__ W1, const float* __restrict__ Wsp, const float* __restrict__ bsp,
    const float* __restrict__ sc1, const float* __restrict__ sh1,
    float* __restrict__ out, int n, int ntiles)
{
    extern __shared__ char lds[];
    char* sW1 = lds + F3_SW1;   // [c][k] bf16, stride 256
    char* sWs = lds + F3_SWS;   // [c][k] bf16, stride 384
    char* sx  = lds + F3_SX;    // [pt][k] bf16, stride 384 (X1 then x2)
    float* ssc = (float*)(lds + F3_SCL);
    float* ssh = ssc + 128;
    float* sbs = ssh + 128;
    int t = threadIdx.x, lane = t & 63, w = t >> 6;
    int pl = lane & 15, qd = lane >> 4;

    // stage W1 (128x128 f32 [k][c]) -> sW1[c][k] bf16, swizzled
#pragma unroll
    for (int it = 0; it < 8; ++it) {
        int e = (it * 512 + t) * 4;
        float4 wv = *(const float4*)(W1 + e);
        int k = e >> 7, c0 = e & 127;
        float wa[4] = {wv.x, wv.y, wv.z, wv.w};
#pragma unroll
        for (int qq = 0; qq < 4; ++qq) {
            int c = c0 + qq;
            *(short*)(sW1 + c * 256 + ((k * 2) ^ ((c & 7) << 4))) = f2bf(wa[qq]);
        }
    }
    // stage Ws (130x128 f32 [k][c]) -> sWs[c][k] bf16, stride 384, swizzled
    for (int it = 0; it < 9; ++it) {
        int e = (it * 512 + t) * 4;
        if (e < 16640) {
            float4 wv = *(const float4*)(Wsp + e);
            int k = e >> 7, c0 = e & 127;
            float wa[4] = {wv.x, wv.y, wv.z, wv.w};
#pragma unroll
            for (int qq = 0; qq < 4; ++qq) {
                int c = c0 + qq;
                *(short*)(sWs + c * 384 + ((k * 2) ^ ((c & 7) << 4))) = f2bf(wa[qq]);
            }
        }
    }
    // zero-pad k-bytes [260,320) for sWs and sx (128 rows each)
    for (int e = t; e < 128 * 15; e += 512) {
        int r = e / 15, qq = e - r * 15;
        int k2 = 260 + 4 * qq;
        *(unsigned int*)(sWs + r * 384 + (k2 ^ ((r & 7) << 4))) = 0u;
        *(unsigned int*)(sx  + r * 384 + (k2 ^ ((r & 7) << 4))) = 0u;
    }
    if (t < 128) { ssc[t] = sc1[t]; ssh[t] = sh1[t]; sbs[t] = bsp[t]; }
    __syncthreads();

    unsigned int szr = (unsigned int)(pl & 7) << 4;
    int rb_ = w * 16 + pl;   // this lane's point-row (owned by wave w)
    for (int tile = blockIdx.x; tile < ntiles; tile += gridDim.x) {
        int base = tile * 128;
        // ---- stage X1 tile [pt][256B of the 384-stride rows] ----
        {
            int p = t >> 2, s = t & 3;
            int i = base + p;
            char* rowp = sx + p * 384;
            unsigned int sz = (unsigned int)(p & 7) << 4;
            uint4 d0, d1, d2, d3;
            if (i < n) {
                const uint4* src = (s < 2)
                    ? (const uint4*)(p0 + (size_t)i * 32 + s * 16)
                    : (const uint4*)(vmaxb + (size_t)vidx[i] * 32 + (s - 2) * 16);
                d0 = src[0]; d1 = src[1]; d2 = src[2]; d3 = src[3];
            } else {
                d0 = d1 = d2 = d3 = make_uint4(0u, 0u, 0u, 0u);
            }
            int k2 = s * 64;
            *(uint4*)(rowp + ((k2 +  0) ^ sz)) = d0;
            *(uint4*)(rowp + ((k2 + 16) ^ sz)) = d1;
            *(uint4*)(rowp + ((k2 + 32) ^ sz)) = d2;
            *(uint4*)(rowp + ((k2 + 48) ^ sz)) = d3;
        }
        __syncthreads();
        // ---- MFMA-1: y1[ch][pt] frags ----
        f32x4 acc1[8];
#pragma unroll
        for (int cb = 0; cb < 8; ++cb) acc1[cb] = (f32x4){0.f, 0.f, 0.f, 0.f};
#pragma unroll
        for (int kc = 0; kc < 4; ++kc) {
            int ko2 = kc * 64 + qd * 16;
            bf16x8 b = *(bf16x8*)(sx + rb_ * 384 + (ko2 ^ szr));
#pragma unroll
            for (int cb = 0; cb < 8; ++cb) {
                int ra_ = cb * 16 + pl;
                bf16x8 a = *(bf16x8*)(sW1 + ra_ * 256 + (ko2 ^ szr));
                acc1[cb] = __builtin_amdgcn_mfma_f32_16x16x32_bf16(a, b, acc1[cb], 0, 0, 0);
            }
        }
        // ---- BN+ReLU in regs -> x2 into own row (no cross-wave barrier needed) ----
#pragma unroll
        for (int cb = 0; cb < 8; ++cb) {
            int ch0 = cb * 16 + qd * 4;
            float v0 = fmaxf(fmaf(acc1[cb][0], ssc[ch0 + 0], ssh[ch0 + 0]), 0.f);
            float v1 = fmaxf(fmaf(acc1[cb][1], ssc[ch0 + 1], ssh[ch0 + 1]), 0.f);
            float v2 = fmaxf(fmaf(acc1[cb][2], ssc[ch0 + 2], ssh[ch0 + 2]), 0.f);
            float v3 = fmaxf(fmaf(acc1[cb][3], ssc[ch0 + 3], ssh[ch0 + 3]), 0.f);
            uint2 o;
            o.x = pk(v0, v1);
            o.y = pk(v2, v3);
            *(uint2*)(sx + rb_ * 384 + ((unsigned int)(cb * 32 + qd * 8) ^ szr)) = o;
        }
        if (qd == 0) { // fsp (ch 128,129) for own row
            int i = base + rb_; if (i >= n) i = n - 1;
            unsigned int fs = x[(size_t)i * 8 + 2];
            *(unsigned int*)(sx + rb_ * 384 + (256u ^ szr)) = fs;
        }
        // ---- MFMA-2: out frags ----
        f32x4 acc2[8];
#pragma unroll
        for (int cb = 0; cb < 8; ++cb) acc2[cb] = (f32x4){0.f, 0.f, 0.f, 0.f};
#pragma unroll
        for (int kc = 0; kc < 5; ++kc) {
            int ko2 = kc * 64 + qd * 16;
            bf16x8 b = *(bf16x8*)(sx + rb_ * 384 + (ko2 ^ szr));
#pragma unroll
            for (int cb = 0; cb < 8; ++cb) {
                int ra_ = cb * 16 + pl;
                bf16x8 a = *(bf16x8*)(sWs + ra_ * 384 + (ko2 ^ szr));
                acc2[cb] = __builtin_amdgcn_mfma_f32_16x16x32_bf16(a, b, acc2[cb], 0, 0, 0);
            }
        }
        int pt = base + rb_;
        if (pt < n) {
            float* orow = out + (size_t)pt * 128 + qd * 4;
#pragma unroll
            for (int cb = 0; cb < 8; ++cb) {
                float4 bb = *(float4*)(sbs + cb * 16 + qd * 4);
                float4 o;
                o.x = fmaxf(acc2[cb][0] + bb.x, 0.f);
                o.y = fmaxf(acc2[cb][1] + bb.y, 0.f);
                o.z = fmaxf(acc2[cb][2] + bb.z, 0.f);
                o.w = fmaxf(acc2[cb][3] + bb.w, 0.f);
                *(float4*)(orow + cb * 16) = o;
            }
        }
        __syncthreads();
    }
}

extern "C" void kernel_launch(void* const* d_in, const int* in_sizes, int n_in,
                              void* d_out, int out_size, void* d_ws, size_t ws_size,
                              hipStream_t stream)
{
    const float* feat = (const float*)d_in[0];
    const int*   coor = (const int*)d_in[1];
    const float* W0   = (const float*)d_in[2];
    const float* g0   = (const float*)d_in[3];
    const float* b0   = (const float*)d_in[4];
    const float* W1   = (const float*)d_in[5];
    const float* g1   = (const float*)d_in[6];
    const float* b1   = (const float*)d_in[7];
    const float* Wsp  = (const float*)d_in[8];
    const float* bsp  = (const float*)d_in[9];
    float* outp = (float*)d_out;

    int n = in_sizes[0] / 4;
    size_t npad = ((size_t)n + 127) & ~127ULL;

    char* ws = (char*)d_ws;
    size_t off = 0;
    auto alloc = [&](size_t bytes) { char* p = ws + off; off = (off + bytes + 255) & ~255ULL; return p; };
    int*          vidx   = (int*)alloc(npad * 4);
    float*        counts = (float*)alloc((size_t)CANVASv * 4);
    float*        sumc   = (float*)alloc((size_t)CANVASv * 12);
    float*        spd    = (float*)alloc((size_t)CANVASv * 4);
    unsigned int* x      = (unsigned int*)alloc(npad * 32);
    unsigned int* p0     = (unsigned int*)alloc(npad * 128);
    unsigned int* vmaxb  = (unsigned int*)alloc((size_t)CANVASv * 128);
    int*          starts = (int*)alloc((size_t)CANVASv * 4);
    int*          perm   = (int*)alloc(npad * 4);
    int*          bsum   = (int*)alloc(1024 * 4);
    int*          boff   = (int*)alloc(1024 * 4);
    float*        partials = (float*)alloc((size_t)NPART * 16384 * 4);
    float*        M1     = (float*)alloc(16384 * 4);
    double*       md0    = (double*)alloc(105 * 8 + 128 * 8);
    double*       s1d    = (double*)((char*)md0 + 105 * 8);
    float*        sc0    = (float*)alloc(64 * 4);
    float*        sh0    = (float*)alloc(64 * 4);
    float*        sc1    = (float*)alloc(128 * 4);
    float*        sh1    = (float*)alloc(128 * 4);
    if (off > ws_size) return;

    hipMemsetAsync(counts, 0, (size_t)CANVASv * 4 * 5, stream);
    hipMemsetAsync(md0, 0, 105 * 8 + 128 * 8, stream);

    int blocksN = (n + 255) / 256;
    k_scatter1<<<blocksN, 256, 0, stream>>>((const float4*)feat, (const int4*)coor, vidx, counts, sumc, n);
    k_scatter2<<<blocksN, 256, 0, stream>>>((const float4*)feat, vidx, counts, sumc, spd, n);
    k_prex<<<512, 256, 0, stream>>>((const float4*)feat, (const int4*)coor, vidx, counts, sumc, spd, x, n);
    k_mom<<<512, 256, 0, stream>>>((const uint4*)x, md0, n);
    k_fin0<<<1, 64, 0, stream>>>(md0, W0, g0, b0, sc0, sh0, n);

    // counting sort by voxel
    k_scanA<<<CANVASv / 1024, 1024, 0, stream>>>(counts, starts, bsum);
    k_scanB<<<1, 1024, 0, stream>>>(bsum, boff);
    k_scanC<<<CANVASv / 1024, 1024, 0, stream>>>(starts, boff);
    k_perm<<<blocksN, 256, 0, stream>>>(vidx, starts, perm, n);
    // per-voxel max + per-point p0 (starts is now inclusive prefix)
    k_vmaxv<<<(CANVASv + 3) / 4, 256, 0, stream>>>(x, W0, sc0, sh0, starts, perm, p0, vmaxb, CANVASv);

    int ntiles = (n + 127) / 128;
    // BN1 stats via M1 = X1^T X1
    k_mom1<<<NPART, 512, 0, stream>>>(p0, vmaxb, vidx, partials, s1d, n, ntiles);
    k_redM1<<<64, 256, 0, stream>>>(partials, M1);
    k_fin1q<<<32, 256, 0, stream>>>(M1, s1d, W1, g1, b1, sc1, sh1, n);

    // fused layer1+BN+ReLU+layer2
    hipFuncSetAttribute((const void*)k_fused3, hipFuncAttributeMaxDynamicSharedMemorySize, F3_LDS);
    k_fused3<<<256, 512, F3_LDS, stream>>>(p0, vmaxb, vidx, x, W1, Wsp, bsp, sc1, sh1, outp, n, ntiles);
}

// Round 8
// 556.567 us; speedup vs baseline: 1.1044x; 1.1044x over previous
//
#include <hip/hip_runtime.h>
#include <hip/hip_bf16.h>

#define NZv 1
#define NYv 400
#define NXv 352
#define Bv 4
#define CANVASv (Bv * NZv * NYv * NXv) /* 563200 = 550 * 1024 */
#define EPSF 0.001f
#define VXF 0.2f
#define VYF 0.2f
#define VZF 4.0f
#define XOFFv 0.1f
#define YOFFv -39.9f
#define ZOFFv -1.0f

typedef __attribute__((ext_vector_type(8))) short bf16x8;
typedef __attribute__((ext_vector_type(4))) float f32x4;
typedef __attribute__((ext_vector_type(2))) unsigned int u32x2;

__device__ __forceinline__ short f2bf(float f) {
    union { __hip_bfloat16 h; short s; } u;
    u.h = __float2bfloat16(f);
    return u.s;
}
__device__ __forceinline__ float bf2f(short s) {
    return __uint_as_float(((unsigned int)(unsigned short)s) << 16);
}
__device__ __forceinline__ unsigned int pk(float a, float b) {
    return (unsigned int)(unsigned short)f2bf(a) | ((unsigned int)(unsigned short)f2bf(b) << 16);
}

// compile-time index tables for the 105 upper-triangle moments (a<=b, a-major)
struct MomTab { signed char a[105]; signed char b[105]; };
constexpr MomTab make_momtab() {
    MomTab m{};
    int idx = 0;
    for (int a = 0; a < 14; ++a)
        for (int b = a; b < 14; ++b) { m.a[idx] = (signed char)a; m.b[idx] = (signed char)b; ++idx; }
    return m;
}
constexpr MomTab MT = make_momtab();

// ---------------- scatter pass 1: count + coord sums ----------------
__global__ void k_scatter1(const float4* __restrict__ feat, const int4* __restrict__ coors,
                           int* __restrict__ vidx, float* __restrict__ counts,
                           float* __restrict__ sumc, int n)
{
    int i = blockIdx.x * blockDim.x + threadIdx.x;
    if (i >= n) return;
    int4 c = coors[i];
    int v = ((c.x * NZv + c.y) * NYv + c.z) * NXv + c.w;
    vidx[i] = v;
    float4 f = feat[i];
    atomicAdd(&counts[v], 1.0f);
    atomicAdd(&sumc[3 * v + 0], f.x);
    atomicAdd(&sumc[3 * v + 1], f.y);
    atomicAdd(&sumc[3 * v + 2], f.z);
}

// ---------------- scatter pass 2: mean-dist sums ----------------
__global__ void k_scatter2(const float4* __restrict__ feat, const int* __restrict__ vidx,
                           const float* __restrict__ counts, const float* __restrict__ sumc,
                           float* __restrict__ spd, int n)
{
    int i = blockIdx.x * blockDim.x + threadIdx.x;
    if (i >= n) return;
    int v = vidx[i];
    float safe = fmaxf(counts[v], 1.0f);
    float inv = 1.0f / safe;
    float4 f = feat[i];
    float dx = f.x - sumc[3 * v + 0] * inv;
    float dy = f.y - sumc[3 * v + 1] * inv;
    float dz = f.z - sumc[3 * v + 2] * inv;
    atomicAdd(&spd[v], sqrtf(dx * dx + dy * dy + dz * dz));
}

// ---------------- prexm: build x bf16[n][16] + fspc + 14x14 moments (static idx) ----------------
__global__ __launch_bounds__(256, 1) void k_prexm(const float4* __restrict__ feat,
                       const int4* __restrict__ coors,
                       const int* __restrict__ vidx, const float* __restrict__ counts,
                       const float* __restrict__ sumc, const float* __restrict__ spd,
                       unsigned int* __restrict__ x, unsigned int* __restrict__ fspc,
                       double* __restrict__ md0, int n)
{
    float acc[105];
#pragma unroll
    for (int e = 0; e < 105; ++e) acc[e] = 0.f;
    int t = threadIdx.x;
    int stride = gridDim.x * blockDim.x;
    for (int i = blockIdx.x * blockDim.x + t; i < n; i += stride) {
        float4 f = feat[i];
        int4 c = coors[i];
        int v = vidx[i];
        float safe = fmaxf(counts[v], 1.0f);
        float inv = 1.0f / safe;
        float vals[14];
        vals[0] = f.x; vals[1] = f.y; vals[2] = f.z; vals[3] = f.w;
        vals[4] = safe / 0.16f;
        vals[5] = spd[v] * inv;
        vals[6] = f.x - sumc[3 * v + 0] * inv;
        vals[7] = f.y - sumc[3 * v + 1] * inv;
        vals[8] = f.z - sumc[3 * v + 2] * inv;
        vals[9]  = f.x - ((float)c.w * VXF + XOFFv);
        vals[10] = f.y - ((float)c.z * VYF + YOFFv);
        vals[11] = f.z - ((float)c.y * VZF + ZOFFv);
        vals[12] = sqrtf(f.x * f.x + f.y * f.y + f.z * f.z);
        vals[13] = 1.0f;
        unsigned int row[8];
#pragma unroll
        for (int q = 0; q < 6; ++q) row[q] = pk(vals[2 * q], vals[2 * q + 1]);
        row[6] = pk(vals[12], 0.f);
        row[7] = 0u;
        uint4* dst = (uint4*)(x + (size_t)i * 8);
        dst[0] = make_uint4(row[0], row[1], row[2], row[3]);
        dst[1] = make_uint4(row[4], row[5], row[6], row[7]);
        fspc[i] = row[2];
        // moments on the bf16-quantized values (consistent with GEMM path)
        float qv[14];
#pragma unroll
        for (int k = 0; k < 13; ++k)
            qv[k] = bf2f((short)((k & 1) ? (row[k >> 1] >> 16) : (row[k >> 1] & 0xFFFF)));
        qv[13] = 1.0f;
#pragma unroll
        for (int e = 0; e < 105; ++e)
            acc[e] = fmaf(qv[MT.a[e]], qv[MT.b[e]], acc[e]);
    }
    __shared__ float wacc[4][105];
    int lane = t & 63, wid = t >> 6;
#pragma unroll
    for (int e = 0; e < 105; ++e) {
        float v = acc[e];
        v += __shfl_xor(v, 1);
        v += __shfl_xor(v, 2);
        v += __shfl_xor(v, 4);
        v += __shfl_xor(v, 8);
        v += __shfl_xor(v, 16);
        v += __shfl_xor(v, 32);
        if (lane == 0) wacc[wid][e] = v;
    }
    __syncthreads();
    if (t < 105) {
        double s = (double)wacc[0][t] + (double)wacc[1][t] + (double)wacc[2][t] + (double)wacc[3][t];
        atomicAdd(&md0[t], s);
    }
}

__device__ __forceinline__ int idx14(int a, int b) { // a<=b
    return a * 14 - a * (a - 1) / 2 + (b - a);
}

// ---------------- fin0: BN0 scale/shift from moments ----------------
__global__ void k_fin0(const double* __restrict__ md0, const float* __restrict__ W0,
                       const float* __restrict__ g0, const float* __restrict__ b0,
                       float* __restrict__ sc0, float* __restrict__ sh0, int n)
{
    __shared__ double mom[105];
    int t = threadIdx.x;
    for (int e = t; e < 105; e += 64) mom[e] = md0[e];
    __syncthreads();
    double nn = (double)n;
    double mu[13];
#pragma unroll
    for (int j = 0; j < 13; ++j) mu[j] = mom[idx14(j, 13)] / nn;
    double wc[13];
#pragma unroll
    for (int j = 0; j < 13; ++j) wc[j] = (double)W0[j * 64 + t];
    double meanc = 0.0, var = 0.0;
#pragma unroll
    for (int j = 0; j < 13; ++j) {
        meanc += mu[j] * wc[j];
        for (int k = 0; k < 13; ++k) {
            int a = j < k ? j : k, b = j < k ? k : j;
            double cov = mom[idx14(a, b)] / nn - mu[j] * mu[k];
            var += cov * wc[j] * wc[k];
        }
    }
    float scale = g0[t] * rsqrtf((float)var + EPSF);
    sc0[t] = scale;
    sh0[t] = b0[t] - (float)meanc * scale;
}

// ---------------- scanA: per-1024-chunk exclusive scan of counts ----------------
__global__ __launch_bounds__(1024) void k_scanA(const float* __restrict__ counts,
                                                int* __restrict__ starts, int* __restrict__ bsum)
{
    __shared__ int sdata[1024];
    int t = threadIdx.x;
    int v = blockIdx.x * 1024 + t;
    int c = (int)counts[v];
    sdata[t] = c;
    __syncthreads();
#pragma unroll
    for (int off = 1; off < 1024; off <<= 1) {
        int val = (t >= off) ? sdata[t - off] : 0;
        __syncthreads();
        sdata[t] += val;
        __syncthreads();
    }
    starts[v] = sdata[t] - c; // exclusive
    if (t == 1023) bsum[blockIdx.x] = sdata[t];
}

// ---------------- scanBC: each block reduces its prefix of bsum, applies offset ----------------
__global__ __launch_bounds__(1024) void k_scanBC(const int* __restrict__ bsum,
                                                 int* __restrict__ starts)
{
    __shared__ int red[16];
    int b = blockIdx.x, t = threadIdx.x;
    int v = (t < b) ? bsum[t] : 0;
    for (int m = 1; m < 64; m <<= 1) v += __shfl_xor(v, m);
    int lane = t & 63, w = t >> 6;
    if (lane == 0) red[w] = v;
    __syncthreads();
    if (t == 0) {
        int s = 0;
#pragma unroll
        for (int q = 0; q < 16; ++q) s += red[q];
        red[0] = s;
    }
    __syncthreads();
    starts[b * 1024 + t] += red[0];
}

// ---------------- perm (starts becomes INCLUSIVE prefix after this) ----------------
__global__ void k_perm(const int* __restrict__ vidx, int* __restrict__ starts,
                       int* __restrict__ perm, int n)
{
    int i = blockIdx.x * blockDim.x + threadIdx.x;
    if (i >= n) return;
    int pos = atomicAdd(&starts[vidx[i]], 1);
    perm[pos] = i;
}

// ---------------- vmaxv: per-voxel max of p0 + per-point p0 write (bf16) ----------------
__global__ __launch_bounds__(256) void k_vmaxv(const unsigned int* __restrict__ x,
    const float* __restrict__ W0, const float* __restrict__ sc0, const float* __restrict__ sh0,
    const int* __restrict__ startsPost, const int* __restrict__ perm,
    unsigned int* __restrict__ p0, unsigned int* __restrict__ vmaxb, int nvox)
{
    int t = threadIdx.x, lane = t & 63, wid = t >> 6;
    int v = blockIdx.x * 4 + wid;
    if (v >= nvox) return;
    int end = startsPost[v];
    int begin = (v > 0) ? startsPost[v - 1] : 0;
    if (begin == end) return;
    float wcol[13];
#pragma unroll
    for (int k = 0; k < 13; ++k) wcol[k] = W0[k * 64 + lane];
    float sc = sc0[lane], sh = sh0[lane];
    float m = 0.f;
    for (int j = begin; j < end; ++j) {
        int i = perm[j];
        const uint4* xr = (const uint4*)(x + (size_t)i * 8);
        uint4 r0 = xr[0], r1 = xr[1];
        unsigned int rw[8] = {r0.x, r0.y, r0.z, r0.w, r1.x, r1.y, r1.z, r1.w};
        float acc = 0.f;
#pragma unroll
        for (int k = 0; k < 13; ++k) {
            float xv = bf2f((short)((k & 1) ? (rw[k >> 1] >> 16) : (rw[k >> 1] & 0xFFFF)));
            acc = fmaf(xv, wcol[k], acc);
        }
        float pv = fmaxf(fmaf(acc, sc, sh), 0.f);
        float pn = __shfl_xor(pv, 1);
        if ((lane & 1) == 0)
            p0[(size_t)i * 32 + (lane >> 1)] = pk(pv, pn);
        m = fmaxf(m, pv);
    }
    float mn = __shfl_xor(m, 1);
    if ((lane & 1) == 0)
        vmaxb[(size_t)v * 32 + (lane >> 1)] = pk(m, mn);
}

// ---------------- gemm1s: X1=[p0|vmax] @ W1 -> y1 bf16, fused BN1 stats ----------------
#define G1_SW1 0
#define G1_SX  32768
#define G1_ST  65536
#define G1_LDS (65536 + 8192)

__global__ __launch_bounds__(512) void k_gemm1s(const unsigned int* __restrict__ p0,
    const unsigned int* __restrict__ vmaxb, const int* __restrict__ vidx,
    const float* __restrict__ W1, unsigned int* __restrict__ y1,
    double* __restrict__ s1d, double* __restrict__ sq1d, int n, int ntiles)
{
    extern __shared__ char lds[];
    char* sW1 = lds + G1_SW1;
    char* sx  = lds + G1_SX;
    int t = threadIdx.x, lane = t & 63, w = t >> 6;
    int pl = lane & 15, qd = lane >> 4;

    // stage W1 (128x128 f32, [k][c]) -> sW1[c][k] bf16, stride 256B, XOR swizzle
#pragma unroll
    for (int it = 0; it < 8; ++it) {
        int e = (it * 512 + t) * 4;
        float4 wv = *(const float4*)(W1 + e);
        int k = e >> 7, c0 = e & 127;
        float wa[4] = {wv.x, wv.y, wv.z, wv.w};
#pragma unroll
        for (int qq = 0; qq < 4; ++qq) {
            int c = c0 + qq;
            *(short*)(sW1 + c * 256 + ((k * 2) ^ ((c & 7) << 4))) = f2bf(wa[qq]);
        }
    }
    __syncthreads();

    float st_s[8][4], st_q[8][4];
#pragma unroll
    for (int cb = 0; cb < 8; ++cb)
#pragma unroll
        for (int jj = 0; jj < 4; ++jj) { st_s[cb][jj] = 0.f; st_q[cb][jj] = 0.f; }

    unsigned int szr = (unsigned int)(pl & 7) << 4;
    int rb_ = w * 16 + pl;
    for (int tile = blockIdx.x; tile < ntiles; tile += gridDim.x) {
        int base = tile * 128;
        {
            int p = t >> 2, s = t & 3;
            int i = base + p;
            char* rowp = sx + p * 256;
            unsigned int sz = (unsigned int)(p & 7) << 4;
            uint4 d0, d1, d2, d3;
            if (i < n) {
                const uint4* src = (s < 2)
                    ? (const uint4*)(p0 + (size_t)i * 32 + s * 16)
                    : (const uint4*)(vmaxb + (size_t)vidx[i] * 32 + (s - 2) * 16);
                d0 = src[0]; d1 = src[1]; d2 = src[2]; d3 = src[3];
            } else {
                d0 = d1 = d2 = d3 = make_uint4(0u, 0u, 0u, 0u);
            }
            int k2 = s * 64;
            *(uint4*)(rowp + ((k2 +  0) ^ sz)) = d0;
            *(uint4*)(rowp + ((k2 + 16) ^ sz)) = d1;
            *(uint4*)(rowp + ((k2 + 32) ^ sz)) = d2;
            *(uint4*)(rowp + ((k2 + 48) ^ sz)) = d3;
        }
        __syncthreads();
        // MFMA: D[row=channel][col=point]  (a=W-frag, b=x-frag)
        f32x4 acc[8];
#pragma unroll
        for (int cb = 0; cb < 8; ++cb) acc[cb] = (f32x4){0.f, 0.f, 0.f, 0.f};
#pragma unroll
        for (int kc = 0; kc < 4; ++kc) {
            int ko2 = kc * 64 + qd * 16;
            bf16x8 b = *(bf16x8*)(sx + rb_ * 256 + (ko2 ^ szr));
#pragma unroll
            for (int cb = 0; cb < 8; ++cb) {
                int ra_ = cb * 16 + pl;
                bf16x8 a = *(bf16x8*)(sW1 + ra_ * 256 + (ko2 ^ szr));
                acc[cb] = __builtin_amdgcn_mfma_f32_16x16x32_bf16(a, b, acc[cb], 0, 0, 0);
            }
        }
        int pt = base + rb_;
        if (pt < n) {
            char* yrow = (char*)y1 + (size_t)pt * 256 + qd * 8;
#pragma unroll
            for (int cb = 0; cb < 8; ++cb) {
                u32x2 o;
                o.x = pk(acc[cb][0], acc[cb][1]);
                o.y = pk(acc[cb][2], acc[cb][3]);
                *(u32x2*)(yrow + cb * 32) = o;
#pragma unroll
                for (int jj = 0; jj < 4; ++jj) {
                    float av = acc[cb][jj];
                    st_s[cb][jj] += av;
                    st_q[cb][jj] = fmaf(av, av, st_q[cb][jj]);
                }
            }
        }
        __syncthreads();
    }
    // ---- stats reduction ----
    float* ssum = (float*)(lds + G1_ST);        // [8][128]
    float* ssq  = ssum + 8 * 128;
#pragma unroll
    for (int cb = 0; cb < 8; ++cb)
#pragma unroll
        for (int jj = 0; jj < 4; ++jj) {
            float sv = st_s[cb][jj], qv = st_q[cb][jj];
            sv += __shfl_xor(sv, 1); qv += __shfl_xor(qv, 1);
            sv += __shfl_xor(sv, 2); qv += __shfl_xor(qv, 2);
            sv += __shfl_xor(sv, 4); qv += __shfl_xor(qv, 4);
            sv += __shfl_xor(sv, 8); qv += __shfl_xor(qv, 8);
            if (pl == 0) {
                int ch = cb * 16 + qd * 4 + jj;
                ssum[w * 128 + ch] = sv;
                ssq[w * 128 + ch] = qv;
            }
        }
    __syncthreads();
    if (t < 128) {
        float s = 0.f, q = 0.f;
#pragma unroll
        for (int ww = 0; ww < 8; ++ww) { s += ssum[ww * 128 + t]; q += ssq[ww * 128 + t]; }
        atomicAdd(&s1d[t], (double)s);
        atomicAdd(&sq1d[t], (double)q);
    }
}

__global__ void k_fin1s(const double* __restrict__ s1d, const double* __restrict__ sq1d,
                        const float* __restrict__ g1, const float* __restrict__ b1,
                        float* __restrict__ sc1, float* __restrict__ sh1, int n)
{
    int c = threadIdx.x;
    double mean = s1d[c] / (double)n;
    double var = sq1d[c] / (double)n - mean * mean;
    float scale = g1[c] * rsqrtf((float)var + EPSF);
    sc1[c] = scale;
    sh1[c] = b1[c] - (float)mean * scale;
}

// ---------------- fused2: BN+ReLU(y1) |fsp -> @ Ws + bs -> ReLU -> out ----------------
#define F2_SWS 0
#define F2_SX  49152
#define F2_SCL (49152 + 24576)
#define F2_LDS (F2_SCL + 1536)

__global__ __launch_bounds__(256) void k_fused2(const uint4* __restrict__ y1,
    const unsigned int* __restrict__ fspc,
    const float* __restrict__ Wsp, const float* __restrict__ bsp,
    const float* __restrict__ sc1, const float* __restrict__ sh1,
    float* __restrict__ out, int n, int ntiles)
{
    extern __shared__ char lds[];
    char* sWs = lds + F2_SWS;
    char* sx  = lds + F2_SX;
    float* ssc = (float*)(lds + F2_SCL);
    float* ssh = ssc + 128;
    float* sbs = ssh + 128;
    int t = threadIdx.x, lane = t & 63, w = t >> 6;
    int pl = lane & 15, qd = lane >> 4;

    for (int it = 0; it < 17; ++it) {
        int e = (it * 256 + t) * 4;
        if (e < 16640) {
            float4 wv = *(const float4*)(Wsp + e);
            int k = e >> 7, c0 = e & 127;
            float wa[4] = {wv.x, wv.y, wv.z, wv.w};
#pragma unroll
            for (int qq = 0; qq < 4; ++qq) {
                int c = c0 + qq;
                *(short*)(sWs + c * 384 + ((k * 2) ^ ((c & 7) << 4))) = f2bf(wa[qq]);
            }
        }
    }
    for (int e = t; e < 128 * 15; e += 256) {
        int r = e / 15, qq = e - r * 15;
        int k2 = 260 + 4 * qq;
        *(unsigned int*)(sWs + r * 384 + (k2 ^ ((r & 7) << 4))) = 0u;
    }
    for (int e = t; e < 64 * 15; e += 256) {
        int r = e / 15, qq = e - r * 15;
        int k2 = 260 + 4 * qq;
        *(unsigned int*)(sx + r * 384 + (k2 ^ ((r & 7) << 4))) = 0u;
    }
    if (t < 128) { ssc[t] = sc1[t]; ssh[t] = sh1[t]; sbs[t] = bsp[t]; }
    __syncthreads();

    unsigned int szr = (unsigned int)(pl & 7) << 4;
    int rb_ = w * 16 + pl;
    for (int tile = blockIdx.x; tile < ntiles; tile += gridDim.x) {
        int base = tile * 64;
        {
            int p = t >> 2, s = t & 3;
            int i = base + p;
            char* rowp = sx + p * 384;
            unsigned int sz = (unsigned int)(p & 7) << 4;
            unsigned int ow[16];
            if (i < n) {
                const uint4* src = (const uint4*)((const char*)y1 + (size_t)i * 256 + s * 64);
                uint4 d0 = src[0], d1 = src[1], d2 = src[2], d3 = src[3];
                unsigned int iw[16] = {d0.x, d0.y, d0.z, d0.w, d1.x, d1.y, d1.z, d1.w,
                                       d2.x, d2.y, d2.z, d2.w, d3.x, d3.y, d3.z, d3.w};
#pragma unroll
                for (int qq = 0; qq < 16; ++qq) {
                    int c = s * 32 + 2 * qq;
                    float a = fmaxf(fmaf(bf2f((short)(iw[qq] & 0xFFFF)), ssc[c], ssh[c]), 0.f);
                    float b = fmaxf(fmaf(bf2f((short)(iw[qq] >> 16)), ssc[c + 1], ssh[c + 1]), 0.f);
                    ow[qq] = pk(a, b);
                }
            } else {
#pragma unroll
                for (int qq = 0; qq < 16; ++qq) ow[qq] = 0u;
            }
            int k2 = s * 64;
#pragma unroll
            for (int qq = 0; qq < 4; ++qq)
                *(uint4*)(rowp + ((k2 + 16 * qq) ^ sz)) =
                    make_uint4(ow[4 * qq], ow[4 * qq + 1], ow[4 * qq + 2], ow[4 * qq + 3]);
        }
        if (t < 64) {
            int i = base + t; if (i >= n) i = n - 1;
            unsigned int fs = fspc[i];
            *(unsigned int*)(sx + t * 384 + (256 ^ ((t & 7) << 4))) = fs;
        }
        __syncthreads();
        f32x4 acc[8];
#pragma unroll
        for (int cb = 0; cb < 8; ++cb) acc[cb] = (f32x4){0.f, 0.f, 0.f, 0.f};
#pragma unroll
        for (int kc = 0; kc < 5; ++kc) {
            int ko2 = kc * 64 + qd * 16;
            bf16x8 b = *(bf16x8*)(sx + rb_ * 384 + (ko2 ^ szr));
#pragma unroll
            for (int cb = 0; cb < 8; ++cb) {
                int ra_ = cb * 16 + pl;
                bf16x8 a = *(bf16x8*)(sWs + ra_ * 384 + (ko2 ^ szr));
                acc[cb] = __builtin_amdgcn_mfma_f32_16x16x32_bf16(a, b, acc[cb], 0, 0, 0);
            }
        }
        int pt = base + rb_;
        if (pt < n) {
            float* orow = out + (size_t)pt * 128 + qd * 4;
#pragma unroll
            for (int cb = 0; cb < 8; ++cb) {
                float4 bb = *(float4*)(sbs + cb * 16 + qd * 4);
                f32x4 o;
                o[0] = fmaxf(acc[cb][0] + bb.x, 0.f);
                o[1] = fmaxf(acc[cb][1] + bb.y, 0.f);
                o[2] = fmaxf(acc[cb][2] + bb.z, 0.f);
                o[3] = fmaxf(acc[cb][3] + bb.w, 0.f);
                __builtin_nontemporal_store(o, (f32x4*)(orow + cb * 16));
            }
        }
        __syncthreads();
    }
}

extern "C" void kernel_launch(void* const* d_in, const int* in_sizes, int n_in,
                              void* d_out, int out_size, void* d_ws, size_t ws_size,
                              hipStream_t stream)
{
    const float* feat = (const float*)d_in[0];
    const int*   coor = (const int*)d_in[1];
    const float* W0   = (const float*)d_in[2];
    const float* g0   = (const float*)d_in[3];
    const float* b0   = (const float*)d_in[4];
    const float* W1   = (const float*)d_in[5];
    const float* g1   = (const float*)d_in[6];
    const float* b1   = (const float*)d_in[7];
    const float* Wsp  = (const float*)d_in[8];
    const float* bsp  = (const float*)d_in[9];
    float* outp = (float*)d_out;

    int n = in_sizes[0] / 4;
    size_t npad = ((size_t)n + 127) & ~127ULL;

    char* ws = (char*)d_ws;
    size_t off = 0;
    auto alloc = [&](size_t bytes) { char* p = ws + off; off = (off + bytes + 255) & ~255ULL; return p; };
    int*          vidx   = (int*)alloc(npad * 4);
    // ---- contiguous zero-init region: counts | sumc | spd | md0+s1d+sq1d ----
    float*        counts = (float*)alloc((size_t)CANVASv * 4);
    float*        sumc   = (float*)alloc((size_t)CANVASv * 12);
    float*        spd    = (float*)alloc((size_t)CANVASv * 4);
    double*       md0    = (double*)alloc(105 * 8 + 256 * 8);
    double*       s1d    = (double*)((char*)md0 + 105 * 8);
    double*       sq1d   = s1d + 128;
    // ---- rest ----
    unsigned int* x      = (unsigned int*)alloc(npad * 32);
    unsigned int* fspc   = (unsigned int*)alloc(npad * 4);
    unsigned int* p0     = (unsigned int*)alloc(npad * 128);
    unsigned int* vmaxb  = (unsigned int*)alloc((size_t)CANVASv * 128);
    unsigned int* y1     = (unsigned int*)alloc(npad * 256);
    int*          starts = (int*)alloc((size_t)CANVASv * 4);
    int*          perm   = (int*)alloc(npad * 4);
    int*          bsum   = (int*)alloc(1024 * 4);
    float*        sc0    = (float*)alloc(64 * 4);
    float*        sh0    = (float*)alloc(64 * 4);
    float*        sc1    = (float*)alloc(128 * 4);
    float*        sh1    = (float*)alloc(128 * 4);
    if (off > ws_size) return;

    // single merged memset: counts..spd (5*CANVASv*4, 256-aligned sizes) + md0/s1d/sq1d
    hipMemsetAsync(counts, 0, (size_t)CANVASv * 4 * 5 + 105 * 8 + 256 * 8, stream);

    int blocksN = (n + 255) / 256;
    k_scatter1<<<blocksN, 256, 0, stream>>>((const float4*)feat, (const int4*)coor, vidx, counts, sumc, n);
    k_scatter2<<<blocksN, 256, 0, stream>>>((const float4*)feat, vidx, counts, sumc, spd, n);
    k_prexm<<<512, 256, 0, stream>>>((const float4*)feat, (const int4*)coor, vidx, counts, sumc, spd, x, fspc, md0, n);
    k_fin0<<<1, 64, 0, stream>>>(md0, W0, g0, b0, sc0, sh0, n);

    // counting sort by voxel
    k_scanA<<<CANVASv / 1024, 1024, 0, stream>>>(counts, starts, bsum);
    k_scanBC<<<CANVASv / 1024, 1024, 0, stream>>>(bsum, starts);
    k_perm<<<blocksN, 256, 0, stream>>>(vidx, starts, perm, n);
    // per-voxel max + per-point p0 (starts is now inclusive prefix)
    k_vmaxv<<<(CANVASv + 3) / 4, 256, 0, stream>>>(x, W0, sc0, sh0, starts, perm, p0, vmaxb, CANVASv);

    int ntiles1 = (n + 127) / 128;
    hipFuncSetAttribute((const void*)k_gemm1s, hipFuncAttributeMaxDynamicSharedMemorySize, G1_LDS);
    k_gemm1s<<<512, 512, G1_LDS, stream>>>(p0, vmaxb, vidx, W1, y1, s1d, sq1d, n, ntiles1);

    k_fin1s<<<1, 128, 0, stream>>>(s1d, sq1d, g1, b1, sc1, sh1, n);

    int ntiles2 = (n + 63) / 64;
    hipFuncSetAttribute((const void*)k_fused2, hipFuncAttributeMaxDynamicSharedMemorySize, F2_LDS);
    k_fused2<<<512, 256, F2_LDS, stream>>>((const uint4*)y1, fspc, Wsp, bsp, sc1, sh1, outp, n, ntiles2);
}

// Round 9
// 434.216 us; speedup vs baseline: 1.4156x; 1.2818x over previous
//
#include <hip/hip_runtime.h>
#include <hip/hip_bf16.h>

#define NZv 1
#define NYv 400
#define NXv 352
#define Bv 4
#define CANVASv (Bv * NZv * NYv * NXv) /* 563200 = 550 * 1024 */
#define EPSF 0.001f
#define VXF 0.2f
#define VYF 0.2f
#define VZF 4.0f
#define XOFFv 0.1f
#define YOFFv -39.9f
#define ZOFFv -1.0f

typedef __attribute__((ext_vector_type(8))) short bf16x8;
typedef __attribute__((ext_vector_type(4))) float f32x4;
typedef __attribute__((ext_vector_type(2))) unsigned int u32x2;

__device__ __forceinline__ short f2bf(float f) {
    union { __hip_bfloat16 h; short s; } u;
    u.h = __float2bfloat16(f);
    return u.s;
}
__device__ __forceinline__ float bf2f(short s) {
    return __uint_as_float(((unsigned int)(unsigned short)s) << 16);
}
__device__ __forceinline__ unsigned int pk(float a, float b) {
    return (unsigned int)(unsigned short)f2bf(a) | ((unsigned int)(unsigned short)f2bf(b) << 16);
}

// compile-time index tables for the 105 upper-triangle moments (a<=b, a-major)
struct MomTab { signed char a[105]; signed char b[105]; };
constexpr MomTab make_momtab() {
    MomTab m{};
    int idx = 0;
    for (int a = 0; a < 14; ++a)
        for (int b = a; b < 14; ++b) { m.a[idx] = (signed char)a; m.b[idx] = (signed char)b; ++idx; }
    return m;
}
constexpr MomTab MT = make_momtab();

// ---------------- scatter1: vidx + counts only ----------------
__global__ void k_scatter1(const int4* __restrict__ coors, int* __restrict__ vidx,
                           float* __restrict__ counts, int n)
{
    int i = blockIdx.x * blockDim.x + threadIdx.x;
    if (i >= n) return;
    int4 c = coors[i];
    int v = ((c.x * NZv + c.y) * NYv + c.z) * NXv + c.w;
    vidx[i] = v;
    atomicAdd(&counts[v], 1.0f);
}

// ---------------- scanA: per-1024-chunk exclusive scan of counts ----------------
__global__ __launch_bounds__(1024) void k_scanA(const float* __restrict__ counts,
                                                int* __restrict__ starts, int* __restrict__ bsum)
{
    __shared__ int sdata[1024];
    int t = threadIdx.x;
    int v = blockIdx.x * 1024 + t;
    int c = (int)counts[v];
    sdata[t] = c;
    __syncthreads();
#pragma unroll
    for (int off = 1; off < 1024; off <<= 1) {
        int val = (t >= off) ? sdata[t - off] : 0;
        __syncthreads();
        sdata[t] += val;
        __syncthreads();
    }
    starts[v] = sdata[t] - c; // exclusive
    if (t == 1023) bsum[blockIdx.x] = sdata[t];
}

// ---------------- scanBC: each block reduces its prefix of bsum, applies offset ----------------
__global__ __launch_bounds__(1024) void k_scanBC(const int* __restrict__ bsum,
                                                 int* __restrict__ starts)
{
    __shared__ int red[16];
    int b = blockIdx.x, t = threadIdx.x;
    int v = (t < b) ? bsum[t] : 0;
    for (int m = 1; m < 64; m <<= 1) v += __shfl_xor(v, m);
    int lane = t & 63, w = t >> 6;
    if (lane == 0) red[w] = v;
    __syncthreads();
    if (t == 0) {
        int s = 0;
#pragma unroll
        for (int q = 0; q < 16; ++q) s += red[q];
        red[0] = s;
    }
    __syncthreads();
    starts[b * 1024 + t] += red[0];
}

// ---------------- perm (starts becomes INCLUSIVE prefix after this) ----------------
__global__ void k_perm(const int* __restrict__ vidx, int* __restrict__ starts,
                       int* __restrict__ perm, int n)
{
    int i = blockIdx.x * blockDim.x + threadIdx.x;
    if (i >= n) return;
    int pos = atomicAdd(&starts[vidx[i]], 1);
    perm[pos] = i;
}

// ---------------- seg: per-voxel mean + mean-dist (no atomics), thread per voxel ----------------
__global__ __launch_bounds__(256) void k_seg(const float4* __restrict__ feat,
                                             const int* __restrict__ startsPost,
                                             const int* __restrict__ perm,
                                             float4* __restrict__ vstat, int nvox)
{
    int stride = gridDim.x * blockDim.x;
    for (int v = blockIdx.x * blockDim.x + threadIdx.x; v < nvox; v += stride) {
        int end = startsPost[v];
        int begin = (v > 0) ? startsPost[v - 1] : 0;
        if (begin == end) continue;
        float sx = 0.f, sy = 0.f, sz = 0.f;
        for (int j = begin; j < end; ++j) {
            float4 f = feat[perm[j]];
            sx += f.x; sy += f.y; sz += f.z;
        }
        float inv = 1.0f / (float)(end - begin);
        float mx = sx * inv, my = sy * inv, mz = sz * inv;
        float pd = 0.f;
        for (int j = begin; j < end; ++j) {
            float4 f = feat[perm[j]];
            float dx = f.x - mx, dy = f.y - my, dz = f.z - mz;
            pd += sqrtf(dx * dx + dy * dy + dz * dz);
        }
        vstat[v] = make_float4(mx, my, mz, pd * inv);
    }
}

// ---------------- prexm: build x bf16[n][16] + fspc + 14x14 moments (static idx) ----------------
__global__ __launch_bounds__(256, 1) void k_prexm(const float4* __restrict__ feat,
                       const int4* __restrict__ coors,
                       const int* __restrict__ vidx, const float* __restrict__ counts,
                       const float4* __restrict__ vstat,
                       unsigned int* __restrict__ x, unsigned int* __restrict__ fspc,
                       double* __restrict__ md0, int n)
{
    float acc[105];
#pragma unroll
    for (int e = 0; e < 105; ++e) acc[e] = 0.f;
    int t = threadIdx.x;
    int stride = gridDim.x * blockDim.x;
    for (int i = blockIdx.x * blockDim.x + t; i < n; i += stride) {
        float4 f = feat[i];
        int4 c = coors[i];
        int v = vidx[i];
        float safe = fmaxf(counts[v], 1.0f);
        float4 vs = vstat[v];
        float vals[14];
        vals[0] = f.x; vals[1] = f.y; vals[2] = f.z; vals[3] = f.w;
        vals[4] = safe / 0.16f;
        vals[5] = vs.w;
        vals[6] = f.x - vs.x;
        vals[7] = f.y - vs.y;
        vals[8] = f.z - vs.z;
        vals[9]  = f.x - ((float)c.w * VXF + XOFFv);
        vals[10] = f.y - ((float)c.z * VYF + YOFFv);
        vals[11] = f.z - ((float)c.y * VZF + ZOFFv);
        vals[12] = sqrtf(f.x * f.x + f.y * f.y + f.z * f.z);
        vals[13] = 1.0f;
        unsigned int row[8];
#pragma unroll
        for (int q = 0; q < 6; ++q) row[q] = pk(vals[2 * q], vals[2 * q + 1]);
        row[6] = pk(vals[12], 0.f);
        row[7] = 0u;
        uint4* dst = (uint4*)(x + (size_t)i * 8);
        dst[0] = make_uint4(row[0], row[1], row[2], row[3]);
        dst[1] = make_uint4(row[4], row[5], row[6], row[7]);
        fspc[i] = row[2];
        // moments on the bf16-quantized values (consistent with GEMM path)
        float qv[14];
#pragma unroll
        for (int k = 0; k < 13; ++k)
            qv[k] = bf2f((short)((k & 1) ? (row[k >> 1] >> 16) : (row[k >> 1] & 0xFFFF)));
        qv[13] = 1.0f;
#pragma unroll
        for (int e = 0; e < 105; ++e)
            acc[e] = fmaf(qv[MT.a[e]], qv[MT.b[e]], acc[e]);
    }
    __shared__ float wacc[4][105];
    int lane = t & 63, wid = t >> 6;
#pragma unroll
    for (int e = 0; e < 105; ++e) {
        float v = acc[e];
        v += __shfl_xor(v, 1);
        v += __shfl_xor(v, 2);
        v += __shfl_xor(v, 4);
        v += __shfl_xor(v, 8);
        v += __shfl_xor(v, 16);
        v += __shfl_xor(v, 32);
        if (lane == 0) wacc[wid][e] = v;
    }
    __syncthreads();
    if (t < 105) {
        double s = (double)wacc[0][t] + (double)wacc[1][t] + (double)wacc[2][t] + (double)wacc[3][t];
        atomicAdd(&md0[t], s);
    }
}

__device__ __forceinline__ int idx14(int a, int b) { // a<=b
    return a * 14 - a * (a - 1) / 2 + (b - a);
}

// ---------------- fin0: BN0 scale/shift from moments ----------------
__global__ void k_fin0(const double* __restrict__ md0, const float* __restrict__ W0,
                       const float* __restrict__ g0, const float* __restrict__ b0,
                       float* __restrict__ sc0, float* __restrict__ sh0, int n)
{
    __shared__ double mom[105];
    int t = threadIdx.x;
    for (int e = t; e < 105; e += 64) mom[e] = md0[e];
    __syncthreads();
    double nn = (double)n;
    double mu[13];
#pragma unroll
    for (int j = 0; j < 13; ++j) mu[j] = mom[idx14(j, 13)] / nn;
    double wc[13];
#pragma unroll
    for (int j = 0; j < 13; ++j) wc[j] = (double)W0[j * 64 + t];
    double meanc = 0.0, var = 0.0;
#pragma unroll
    for (int j = 0; j < 13; ++j) {
        meanc += mu[j] * wc[j];
        for (int k = 0; k < 13; ++k) {
            int a = j < k ? j : k, b = j < k ? k : j;
            double cov = mom[idx14(a, b)] / nn - mu[j] * mu[k];
            var += cov * wc[j] * wc[k];
        }
    }
    float scale = g0[t] * rsqrtf((float)var + EPSF);
    sc0[t] = scale;
    sh0[t] = b0[t] - (float)meanc * scale;
}

// ---------------- vmaxv: persistent waves; per-voxel max of p0 + per-point p0 write ----------------
__global__ __launch_bounds__(256) void k_vmaxv(const unsigned int* __restrict__ x,
    const float* __restrict__ W0, const float* __restrict__ sc0, const float* __restrict__ sh0,
    const int* __restrict__ startsPost, const int* __restrict__ perm,
    unsigned int* __restrict__ p0, unsigned int* __restrict__ vmaxb, int nvox)
{
    int t = threadIdx.x, lane = t & 63, wid = t >> 6;
    float wcol[13];
#pragma unroll
    for (int k = 0; k < 13; ++k) wcol[k] = W0[k * 64 + lane];
    float sc = sc0[lane], sh = sh0[lane];
    int nw = gridDim.x * 4;
    for (int v = blockIdx.x * 4 + wid; v < nvox; v += nw) {
        int end = startsPost[v];
        int begin = (v > 0) ? startsPost[v - 1] : 0;
        if (begin == end) continue;
        float m = 0.f;
        for (int j = begin; j < end; ++j) {
            int i = perm[j];
            const uint4* xr = (const uint4*)(x + (size_t)i * 8);
            uint4 r0 = xr[0], r1 = xr[1];
            unsigned int rw[8] = {r0.x, r0.y, r0.z, r0.w, r1.x, r1.y, r1.z, r1.w};
            float acc = 0.f;
#pragma unroll
            for (int k = 0; k < 13; ++k) {
                float xv = bf2f((short)((k & 1) ? (rw[k >> 1] >> 16) : (rw[k >> 1] & 0xFFFF)));
                acc = fmaf(xv, wcol[k], acc);
            }
            float pv = fmaxf(fmaf(acc, sc, sh), 0.f);
            float pn = __shfl_xor(pv, 1);
            if ((lane & 1) == 0)
                p0[(size_t)i * 32 + (lane >> 1)] = pk(pv, pn);
            m = fmaxf(m, pv);
        }
        float mn = __shfl_xor(m, 1);
        if ((lane & 1) == 0)
            vmaxb[(size_t)v * 32 + (lane >> 1)] = pk(m, mn);
    }
}

// ---------------- gemm1s: X1=[p0|vmax] @ W1 -> y1 bf16, fused BN1 stats ----------------
#define G1_SW1 0
#define G1_SX  32768
#define G1_ST  65536
#define G1_LDS (65536 + 8192)

__global__ __launch_bounds__(512) void k_gemm1s(const unsigned int* __restrict__ p0,
    const unsigned int* __restrict__ vmaxb, const int* __restrict__ vidx,
    const float* __restrict__ W1, unsigned int* __restrict__ y1,
    double* __restrict__ s1d, double* __restrict__ sq1d, int n, int ntiles)
{
    extern __shared__ char lds[];
    char* sW1 = lds + G1_SW1;
    char* sx  = lds + G1_SX;
    int t = threadIdx.x, lane = t & 63, w = t >> 6;
    int pl = lane & 15, qd = lane >> 4;

    // stage W1 (128x128 f32, [k][c]) -> sW1[c][k] bf16, stride 256B, XOR swizzle
#pragma unroll
    for (int it = 0; it < 8; ++it) {
        int e = (it * 512 + t) * 4;
        float4 wv = *(const float4*)(W1 + e);
        int k = e >> 7, c0 = e & 127;
        float wa[4] = {wv.x, wv.y, wv.z, wv.w};
#pragma unroll
        for (int qq = 0; qq < 4; ++qq) {
            int c = c0 + qq;
            *(short*)(sW1 + c * 256 + ((k * 2) ^ ((c & 7) << 4))) = f2bf(wa[qq]);
        }
    }
    __syncthreads();

    float st_s[8][4], st_q[8][4];
#pragma unroll
    for (int cb = 0; cb < 8; ++cb)
#pragma unroll
        for (int jj = 0; jj < 4; ++jj) { st_s[cb][jj] = 0.f; st_q[cb][jj] = 0.f; }

    unsigned int szr = (unsigned int)(pl & 7) << 4;
    int rb_ = w * 16 + pl;
    for (int tile = blockIdx.x; tile < ntiles; tile += gridDim.x) {
        int base = tile * 128;
        {
            int p = t >> 2, s = t & 3;
            int i = base + p;
            char* rowp = sx + p * 256;
            unsigned int sz = (unsigned int)(p & 7) << 4;
            uint4 d0, d1, d2, d3;
            if (i < n) {
                const uint4* src = (s < 2)
                    ? (const uint4*)(p0 + (size_t)i * 32 + s * 16)
                    : (const uint4*)(vmaxb + (size_t)vidx[i] * 32 + (s - 2) * 16);
                d0 = src[0]; d1 = src[1]; d2 = src[2]; d3 = src[3];
            } else {
                d0 = d1 = d2 = d3 = make_uint4(0u, 0u, 0u, 0u);
            }
            int k2 = s * 64;
            *(uint4*)(rowp + ((k2 +  0) ^ sz)) = d0;
            *(uint4*)(rowp + ((k2 + 16) ^ sz)) = d1;
            *(uint4*)(rowp + ((k2 + 32) ^ sz)) = d2;
            *(uint4*)(rowp + ((k2 + 48) ^ sz)) = d3;
        }
        __syncthreads();
        // MFMA: D[row=channel][col=point]  (a=W-frag, b=x-frag)
        f32x4 acc[8];
#pragma unroll
        for (int cb = 0; cb < 8; ++cb) acc[cb] = (f32x4){0.f, 0.f, 0.f, 0.f};
#pragma unroll
        for (int kc = 0; kc < 4; ++kc) {
            int ko2 = kc * 64 + qd * 16;
            bf16x8 b = *(bf16x8*)(sx + rb_ * 256 + (ko2 ^ szr));
#pragma unroll
            for (int cb = 0; cb < 8; ++cb) {
                int ra_ = cb * 16 + pl;
                bf16x8 a = *(bf16x8*)(sW1 + ra_ * 256 + (ko2 ^ szr));
                acc[cb] = __builtin_amdgcn_mfma_f32_16x16x32_bf16(a, b, acc[cb], 0, 0, 0);
            }
        }
        int pt = base + rb_;
        if (pt < n) {
            char* yrow = (char*)y1 + (size_t)pt * 256 + qd * 8;
#pragma unroll
            for (int cb = 0; cb < 8; ++cb) {
                u32x2 o;
                o.x = pk(acc[cb][0], acc[cb][1]);
                o.y = pk(acc[cb][2], acc[cb][3]);
                *(u32x2*)(yrow + cb * 32) = o;
#pragma unroll
                for (int jj = 0; jj < 4; ++jj) {
                    float av = acc[cb][jj];
                    st_s[cb][jj] += av;
                    st_q[cb][jj] = fmaf(av, av, st_q[cb][jj]);
                }
            }
        }
        __syncthreads();
    }
    // ---- stats reduction ----
    float* ssum = (float*)(lds + G1_ST);        // [8][128]
    float* ssq  = ssum + 8 * 128;
#pragma unroll
    for (int cb = 0; cb < 8; ++cb)
#pragma unroll
        for (int jj = 0; jj < 4; ++jj) {
            float sv = st_s[cb][jj], qv = st_q[cb][jj];
            sv += __shfl_xor(sv, 1); qv += __shfl_xor(qv, 1);
            sv += __shfl_xor(sv, 2); qv += __shfl_xor(qv, 2);
            sv += __shfl_xor(sv, 4); qv += __shfl_xor(qv, 4);
            sv += __shfl_xor(sv, 8); qv += __shfl_xor(qv, 8);
            if (pl == 0) {
                int ch = cb * 16 + qd * 4 + jj;
                ssum[w * 128 + ch] = sv;
                ssq[w * 128 + ch] = qv;
            }
        }
    __syncthreads();
    if (t < 128) {
        float s = 0.f, q = 0.f;
#pragma unroll
        for (int ww = 0; ww < 8; ++ww) { s += ssum[ww * 128 + t]; q += ssq[ww * 128 + t]; }
        atomicAdd(&s1d[t], (double)s);
        atomicAdd(&sq1d[t], (double)q);
    }
}

__global__ void k_fin1s(const double* __restrict__ s1d, const double* __restrict__ sq1d,
                        const float* __restrict__ g1, const float* __restrict__ b1,
                        float* __restrict__ sc1, float* __restrict__ sh1, int n)
{
    int c = threadIdx.x;
    double mean = s1d[c] / (double)n;
    double var = sq1d[c] / (double)n - mean * mean;
    float scale = g1[c] * rsqrtf((float)var + EPSF);
    sc1[c] = scale;
    sh1[c] = b1[c] - (float)mean * scale;
}

// ---------------- fused2: BN+ReLU(y1) |fsp -> @ Ws + bs -> ReLU -> out ----------------
#define F2_SWS 0
#define F2_SX  49152
#define F2_SCL (49152 + 24576)
#define F2_LDS (F2_SCL + 1536)

__global__ __launch_bounds__(256) void k_fused2(const uint4* __restrict__ y1,
    const unsigned int* __restrict__ fspc,
    const float* __restrict__ Wsp, const float* __restrict__ bsp,
    const float* __restrict__ sc1, const float* __restrict__ sh1,
    float* __restrict__ out, int n, int ntiles)
{
    extern __shared__ char lds[];
    char* sWs = lds + F2_SWS;
    char* sx  = lds + F2_SX;
    float* ssc = (float*)(lds + F2_SCL);
    float* ssh = ssc + 128;
    float* sbs = ssh + 128;
    int t = threadIdx.x, lane = t & 63, w = t >> 6;
    int pl = lane & 15, qd = lane >> 4;

    for (int it = 0; it < 17; ++it) {
        int e = (it * 256 + t) * 4;
        if (e < 16640) {
            float4 wv = *(const float4*)(Wsp + e);
            int k = e >> 7, c0 = e & 127;
            float wa[4] = {wv.x, wv.y, wv.z, wv.w};
#pragma unroll
            for (int qq = 0; qq < 4; ++qq) {
                int c = c0 + qq;
                *(short*)(sWs + c * 384 + ((k * 2) ^ ((c & 7) << 4))) = f2bf(wa[qq]);
            }
        }
    }
    for (int e = t; e < 128 * 15; e += 256) {
        int r = e / 15, qq = e - r * 15;
        int k2 = 260 + 4 * qq;
        *(unsigned int*)(sWs + r * 384 + (k2 ^ ((r & 7) << 4))) = 0u;
    }
    for (int e = t; e < 64 * 15; e += 256) {
        int r = e / 15, qq = e - r * 15;
        int k2 = 260 + 4 * qq;
        *(unsigned int*)(sx + r * 384 + (k2 ^ ((r & 7) << 4))) = 0u;
    }
    if (t < 128) { ssc[t] = sc1[t]; ssh[t] = sh1[t]; sbs[t] = bsp[t]; }
    __syncthreads();

    unsigned int szr = (unsigned int)(pl & 7) << 4;
    int rb_ = w * 16 + pl;
    for (int tile = blockIdx.x; tile < ntiles; tile += gridDim.x) {
        int base = tile * 64;
        {
            int p = t >> 2, s = t & 3;
            int i = base + p;
            char* rowp = sx + p * 384;
            unsigned int sz = (unsigned int)(p & 7) << 4;
            unsigned int ow[16];
            if (i < n) {
                const uint4* src = (const uint4*)((const char*)y1 + (size_t)i * 256 + s * 64);
                uint4 d0 = src[0], d1 = src[1], d2 = src[2], d3 = src[3];
                unsigned int iw[16] = {d0.x, d0.y, d0.z, d0.w, d1.x, d1.y, d1.z, d1.w,
                                       d2.x, d2.y, d2.z, d2.w, d3.x, d3.y, d3.z, d3.w};
#pragma unroll
                for (int qq = 0; qq < 16; ++qq) {
                    int c = s * 32 + 2 * qq;
                    float a = fmaxf(fmaf(bf2f((short)(iw[qq] & 0xFFFF)), ssc[c], ssh[c]), 0.f);
                    float b = fmaxf(fmaf(bf2f((short)(iw[qq] >> 16)), ssc[c + 1], ssh[c + 1]), 0.f);
                    ow[qq] = pk(a, b);
                }
            } else {
#pragma unroll
                for (int qq = 0; qq < 16; ++qq) ow[qq] = 0u;
            }
            int k2 = s * 64;
#pragma unroll
            for (int qq = 0; qq < 4; ++qq)
                *(uint4*)(rowp + ((k2 + 16 * qq) ^ sz)) =
                    make_uint4(ow[4 * qq], ow[4 * qq + 1], ow[4 * qq + 2], ow[4 * qq + 3]);
        }
        if (t < 64) {
            int i = base + t; if (i >= n) i = n - 1;
            unsigned int fs = fspc[i];
            *(unsigned int*)(sx + t * 384 + (256 ^ ((t & 7) << 4))) = fs;
        }
        __syncthreads();
        f32x4 acc[8];
#pragma unroll
        for (int cb = 0; cb < 8; ++cb) acc[cb] = (f32x4){0.f, 0.f, 0.f, 0.f};
#pragma unroll
        for (int kc = 0; kc < 5; ++kc) {
            int ko2 = kc * 64 + qd * 16;
            bf16x8 b = *(bf16x8*)(sx + rb_ * 384 + (ko2 ^ szr));
#pragma unroll
            for (int cb = 0; cb < 8; ++cb) {
                int ra_ = cb * 16 + pl;
                bf16x8 a = *(bf16x8*)(sWs + ra_ * 384 + (ko2 ^ szr));
                acc[cb] = __builtin_amdgcn_mfma_f32_16x16x32_bf16(a, b, acc[cb], 0, 0, 0);
            }
        }
        int pt = base + rb_;
        if (pt < n) {
            float* orow = out + (size_t)pt * 128 + qd * 4;
#pragma unroll
            for (int cb = 0; cb < 8; ++cb) {
                float4 bb = *(float4*)(sbs + cb * 16 + qd * 4);
                f32x4 o;
                o[0] = fmaxf(acc[cb][0] + bb.x, 0.f);
                o[1] = fmaxf(acc[cb][1] + bb.y, 0.f);
                o[2] = fmaxf(acc[cb][2] + bb.z, 0.f);
                o[3] = fmaxf(acc[cb][3] + bb.w, 0.f);
                __builtin_nontemporal_store(o, (f32x4*)(orow + cb * 16));
            }
        }
        __syncthreads();
    }
}

extern "C" void kernel_launch(void* const* d_in, const int* in_sizes, int n_in,
                              void* d_out, int out_size, void* d_ws, size_t ws_size,
                              hipStream_t stream)
{
    const float* feat = (const float*)d_in[0];
    const int*   coor = (const int*)d_in[1];
    const float* W0   = (const float*)d_in[2];
    const float* g0   = (const float*)d_in[3];
    const float* b0   = (const float*)d_in[4];
    const float* W1   = (const float*)d_in[5];
    const float* g1   = (const float*)d_in[6];
    const float* b1   = (const float*)d_in[7];
    const float* Wsp  = (const float*)d_in[8];
    const float* bsp  = (const float*)d_in[9];
    float* outp = (float*)d_out;

    int n = in_sizes[0] / 4;
    size_t npad = ((size_t)n + 127) & ~127ULL;

    char* ws = (char*)d_ws;
    size_t off = 0;
    auto alloc = [&](size_t bytes) { char* p = ws + off; off = (off + bytes + 255) & ~255ULL; return p; };
    int*          vidx   = (int*)alloc(npad * 4);
    // ---- contiguous zero-init region: counts | md0+s1d+sq1d ----
    float*        counts = (float*)alloc((size_t)CANVASv * 4);
    double*       md0    = (double*)alloc(105 * 8 + 256 * 8);
    double*       s1d    = (double*)((char*)md0 + 105 * 8);
    double*       sq1d   = s1d + 128;
    // ---- rest ----
    float4*       vstat  = (float4*)alloc((size_t)CANVASv * 16);
    unsigned int* x      = (unsigned int*)alloc(npad * 32);
    unsigned int* fspc   = (unsigned int*)alloc(npad * 4);
    unsigned int* p0     = (unsigned int*)alloc(npad * 128);
    unsigned int* vmaxb  = (unsigned int*)alloc((size_t)CANVASv * 128);
    unsigned int* y1     = (unsigned int*)alloc(npad * 256);
    int*          starts = (int*)alloc((size_t)CANVASv * 4);
    int*          perm   = (int*)alloc(npad * 4);
    int*          bsum   = (int*)alloc(1024 * 4);
    float*        sc0    = (float*)alloc(64 * 4);
    float*        sh0    = (float*)alloc(64 * 4);
    float*        sc1    = (float*)alloc(128 * 4);
    float*        sh1    = (float*)alloc(128 * 4);
    if (off > ws_size) return;

    // single merged memset: counts + md0/s1d/sq1d
    hipMemsetAsync(counts, 0, (size_t)CANVASv * 4 + 105 * 8 + 256 * 8, stream);

    int blocksN = (n + 255) / 256;
    k_scatter1<<<blocksN, 256, 0, stream>>>((const int4*)coor, vidx, counts, n);

    // counting sort by voxel
    k_scanA<<<CANVASv / 1024, 1024, 0, stream>>>(counts, starts, bsum);
    k_scanBC<<<CANVASv / 1024, 1024, 0, stream>>>(bsum, starts);
    k_perm<<<blocksN, 256, 0, stream>>>(vidx, starts, perm, n);

    // per-voxel mean + mean-dist (segmented, no atomics)
    k_seg<<<1024, 256, 0, stream>>>((const float4*)feat, starts, perm, vstat, CANVASv);

    // build x + moments
    k_prexm<<<512, 256, 0, stream>>>((const float4*)feat, (const int4*)coor, vidx, counts, vstat, x, fspc, md0, n);
    k_fin0<<<1, 64, 0, stream>>>(md0, W0, g0, b0, sc0, sh0, n);

    // per-voxel max + per-point p0 (persistent waves)
    k_vmaxv<<<2048, 256, 0, stream>>>(x, W0, sc0, sh0, starts, perm, p0, vmaxb, CANVASv);

    int ntiles1 = (n + 127) / 128;
    hipFuncSetAttribute((const void*)k_gemm1s, hipFuncAttributeMaxDynamicSharedMemorySize, G1_LDS);
    k_gemm1s<<<512, 512, G1_LDS, stream>>>(p0, vmaxb, vidx, W1, y1, s1d, sq1d, n, ntiles1);

    k_fin1s<<<1, 128, 0, stream>>>(s1d, sq1d, g1, b1, sc1, sh1, n);

    int ntiles2 = (n + 63) / 64;
    hipFuncSetAttribute((const void*)k_fused2, hipFuncAttributeMaxDynamicSharedMemorySize, F2_LDS);
    k_fused2<<<512, 256, F2_LDS, stream>>>((const uint4*)y1, fspc, Wsp, bsp, sc1, sh1, outp, n, ntiles2);
}

// Round 10
// 408.902 us; speedup vs baseline: 1.5033x; 1.0619x over previous
//
#include <hip/hip_runtime.h>
#include <hip/hip_bf16.h>

#define NZv 1
#define NYv 400
#define NXv 352
#define Bv 4
#define CANVASv (Bv * NZv * NYv * NXv) /* 563200 = 550 * 1024 */
#define EPSF 0.001f
#define VXF 0.2f
#define VYF 0.2f
#define VZF 4.0f
#define XOFFv 0.1f
#define YOFFv -39.9f
#define ZOFFv -1.0f

typedef __attribute__((ext_vector_type(8))) short bf16x8;
typedef __attribute__((ext_vector_type(4))) float f32x4;
typedef __attribute__((ext_vector_type(2))) unsigned int u32x2;

__device__ __forceinline__ short f2bf(float f) {
    union { __hip_bfloat16 h; short s; } u;
    u.h = __float2bfloat16(f);
    return u.s;
}
__device__ __forceinline__ float bf2f(short s) {
    return __uint_as_float(((unsigned int)(unsigned short)s) << 16);
}
__device__ __forceinline__ unsigned int pk(float a, float b) {
    return (unsigned int)(unsigned short)f2bf(a) | ((unsigned int)(unsigned short)f2bf(b) << 16);
}

// compile-time index tables for the 105 upper-triangle moments (a<=b, a-major)
struct MomTab { signed char a[105]; signed char b[105]; };
constexpr MomTab make_momtab() {
    MomTab m{};
    int idx = 0;
    for (int a = 0; a < 14; ++a)
        for (int b = a; b < 14; ++b) { m.a[idx] = (signed char)a; m.b[idx] = (signed char)b; ++idx; }
    return m;
}
constexpr MomTab MT = make_momtab();

// ---------------- scatter1: vidx + counts only ----------------
__global__ void k_scatter1(const int4* __restrict__ coors, int* __restrict__ vidx,
                           float* __restrict__ counts, int n)
{
    int i = blockIdx.x * blockDim.x + threadIdx.x;
    if (i >= n) return;
    int4 c = coors[i];
    int v = ((c.x * NZv + c.y) * NYv + c.z) * NXv + c.w;
    vidx[i] = v;
    atomicAdd(&counts[v], 1.0f);
}

// ---------------- scanA: per-1024-chunk exclusive scan of counts ----------------
__global__ __launch_bounds__(1024) void k_scanA(const float* __restrict__ counts,
                                                int* __restrict__ starts, int* __restrict__ bsum)
{
    __shared__ int sdata[1024];
    int t = threadIdx.x;
    int v = blockIdx.x * 1024 + t;
    int c = (int)counts[v];
    sdata[t] = c;
    __syncthreads();
#pragma unroll
    for (int off = 1; off < 1024; off <<= 1) {
        int val = (t >= off) ? sdata[t - off] : 0;
        __syncthreads();
        sdata[t] += val;
        __syncthreads();
    }
    starts[v] = sdata[t] - c; // exclusive
    if (t == 1023) bsum[blockIdx.x] = sdata[t];
}

// ---------------- scanBC: each block reduces its prefix of bsum, applies offset ----------------
__global__ __launch_bounds__(1024) void k_scanBC(const int* __restrict__ bsum,
                                                 int* __restrict__ starts)
{
    __shared__ int red[16];
    int b = blockIdx.x, t = threadIdx.x;
    int v = (t < b) ? bsum[t] : 0;
    for (int m = 1; m < 64; m <<= 1) v += __shfl_xor(v, m);
    int lane = t & 63, w = t >> 6;
    if (lane == 0) red[w] = v;
    __syncthreads();
    if (t == 0) {
        int s = 0;
#pragma unroll
        for (int q = 0; q < 16; ++q) s += red[q];
        red[0] = s;
    }
    __syncthreads();
    starts[b * 1024 + t] += red[0];
}

// ---------------- perm (starts becomes INCLUSIVE prefix after this) ----------------
__global__ void k_perm(const int* __restrict__ vidx, int* __restrict__ starts,
                       int* __restrict__ perm, int n)
{
    int i = blockIdx.x * blockDim.x + threadIdx.x;
    if (i >= n) return;
    int pos = atomicAdd(&starts[vidx[i]], 1);
    perm[pos] = i;
}

// ---------------- seg: per-voxel mean + mean-dist (no atomics), thread per voxel ----------------
__global__ __launch_bounds__(256) void k_seg(const float4* __restrict__ feat,
                                             const int* __restrict__ startsPost,
                                             const int* __restrict__ perm,
                                             float4* __restrict__ vstat, int nvox)
{
    int stride = gridDim.x * blockDim.x;
    for (int v = blockIdx.x * blockDim.x + threadIdx.x; v < nvox; v += stride) {
        int end = startsPost[v];
        int begin = (v > 0) ? startsPost[v - 1] : 0;
        if (begin == end) continue;
        float sx = 0.f, sy = 0.f, sz = 0.f;
        for (int j = begin; j < end; ++j) {
            float4 f = feat[perm[j]];
            sx += f.x; sy += f.y; sz += f.z;
        }
        float inv = 1.0f / (float)(end - begin);
        float mx = sx * inv, my = sy * inv, mz = sz * inv;
        float pd = 0.f;
        for (int j = begin; j < end; ++j) {
            float4 f = feat[perm[j]];
            float dx = f.x - mx, dy = f.y - my, dz = f.z - mz;
            pd += sqrtf(dx * dx + dy * dy + dz * dz);
        }
        vstat[v] = make_float4(mx, my, mz, pd * inv);
    }
}

// ---------------- prexm: build x bf16[n][16] + fspc + 14x14 moments (static idx) ----------------
__global__ __launch_bounds__(256, 1) void k_prexm(const float4* __restrict__ feat,
                       const int4* __restrict__ coors,
                       const int* __restrict__ vidx, const float* __restrict__ counts,
                       const float4* __restrict__ vstat,
                       unsigned int* __restrict__ x, unsigned int* __restrict__ fspc,
                       double* __restrict__ md0, int n)
{
    float acc[105];
#pragma unroll
    for (int e = 0; e < 105; ++e) acc[e] = 0.f;
    int t = threadIdx.x;
    int stride = gridDim.x * blockDim.x;
    for (int i = blockIdx.x * blockDim.x + t; i < n; i += stride) {
        float4 f = feat[i];
        int4 c = coors[i];
        int v = vidx[i];
        float safe = fmaxf(counts[v], 1.0f);
        float4 vs = vstat[v];
        float vals[14];
        vals[0] = f.x; vals[1] = f.y; vals[2] = f.z; vals[3] = f.w;
        vals[4] = safe / 0.16f;
        vals[5] = vs.w;
        vals[6] = f.x - vs.x;
        vals[7] = f.y - vs.y;
        vals[8] = f.z - vs.z;
        vals[9]  = f.x - ((float)c.w * VXF + XOFFv);
        vals[10] = f.y - ((float)c.z * VYF + YOFFv);
        vals[11] = f.z - ((float)c.y * VZF + ZOFFv);
        vals[12] = sqrtf(f.x * f.x + f.y * f.y + f.z * f.z);
        vals[13] = 1.0f;
        unsigned int row[8];
#pragma unroll
        for (int q = 0; q < 6; ++q) row[q] = pk(vals[2 * q], vals[2 * q + 1]);
        row[6] = pk(vals[12], 0.f);
        row[7] = 0u;
        uint4* dst = (uint4*)(x + (size_t)i * 8);
        dst[0] = make_uint4(row[0], row[1], row[2], row[3]);
        dst[1] = make_uint4(row[4], row[5], row[6], row[7]);
        fspc[i] = row[2];
        // moments on the bf16-quantized values (consistent with GEMM path)
        float qv[14];
#pragma unroll
        for (int k = 0; k < 13; ++k)
            qv[k] = bf2f((short)((k & 1) ? (row[k >> 1] >> 16) : (row[k >> 1] & 0xFFFF)));
        qv[13] = 1.0f;
#pragma unroll
        for (int e = 0; e < 105; ++e)
            acc[e] = fmaf(qv[MT.a[e]], qv[MT.b[e]], acc[e]);
    }
    __shared__ float wacc[4][105];
    int lane = t & 63, wid = t >> 6;
#pragma unroll
    for (int e = 0; e < 105; ++e) {
        float v = acc[e];
        v += __shfl_xor(v, 1);
        v += __shfl_xor(v, 2);
        v += __shfl_xor(v, 4);
        v += __shfl_xor(v, 8);
        v += __shfl_xor(v, 16);
        v += __shfl_xor(v, 32);
        if (lane == 0) wacc[wid][e] = v;
    }
    __syncthreads();
    if (t < 105) {
        double s = (double)wacc[0][t] + (double)wacc[1][t] + (double)wacc[2][t] + (double)wacc[3][t];
        atomicAdd(&md0[t], s);
    }
}

__device__ __forceinline__ int idx14(int a, int b) { // a<=b
    return a * 14 - a * (a - 1) / 2 + (b - a);
}

// ---------------- fin0: BN0 scale/shift from moments ----------------
__global__ void k_fin0(const double* __restrict__ md0, const float* __restrict__ W0,
                       const float* __restrict__ g0, const float* __restrict__ b0,
                       float* __restrict__ sc0, float* __restrict__ sh0, int n)
{
    __shared__ double mom[105];
    int t = threadIdx.x;
    for (int e = t; e < 105; e += 64) mom[e] = md0[e];
    __syncthreads();
    double nn = (double)n;
    double mu[13];
#pragma unroll
    for (int j = 0; j < 13; ++j) mu[j] = mom[idx14(j, 13)] / nn;
    double wc[13];
#pragma unroll
    for (int j = 0; j < 13; ++j) wc[j] = (double)W0[j * 64 + t];
    double meanc = 0.0, var = 0.0;
#pragma unroll
    for (int j = 0; j < 13; ++j) {
        meanc += mu[j] * wc[j];
        for (int k = 0; k < 13; ++k) {
            int a = j < k ? j : k, b = j < k ? k : j;
            double cov = mom[idx14(a, b)] / nn - mu[j] * mu[k];
            var += cov * wc[j] * wc[k];
        }
    }
    float scale = g0[t] * rsqrtf((float)var + EPSF);
    sc0[t] = scale;
    sh0[t] = b0[t] - (float)meanc * scale;
}

// ---------------- vmaxv: persistent waves; per-voxel max of p0 + per-point p0 write ----------------
__global__ __launch_bounds__(256) void k_vmaxv(const unsigned int* __restrict__ x,
    const float* __restrict__ W0, const float* __restrict__ sc0, const float* __restrict__ sh0,
    const int* __restrict__ startsPost, const int* __restrict__ perm,
    unsigned int* __restrict__ p0, unsigned int* __restrict__ vmaxb, int nvox)
{
    int t = threadIdx.x, lane = t & 63, wid = t >> 6;
    float wcol[13];
#pragma unroll
    for (int k = 0; k < 13; ++k) wcol[k] = W0[k * 64 + lane];
    float sc = sc0[lane], sh = sh0[lane];
    int nw = gridDim.x * 4;
    for (int v = blockIdx.x * 4 + wid; v < nvox; v += nw) {
        int end = startsPost[v];
        int begin = (v > 0) ? startsPost[v - 1] : 0;
        if (begin == end) continue;
        float m = 0.f;
        for (int j = begin; j < end; ++j) {
            int i = perm[j];
            const uint4* xr = (const uint4*)(x + (size_t)i * 8);
            uint4 r0 = xr[0], r1 = xr[1];
            unsigned int rw[8] = {r0.x, r0.y, r0.z, r0.w, r1.x, r1.y, r1.z, r1.w};
            float acc = 0.f;
#pragma unroll
            for (int k = 0; k < 13; ++k) {
                float xv = bf2f((short)((k & 1) ? (rw[k >> 1] >> 16) : (rw[k >> 1] & 0xFFFF)));
                acc = fmaf(xv, wcol[k], acc);
            }
            float pv = fmaxf(fmaf(acc, sc, sh), 0.f);
            float pn = __shfl_xor(pv, 1);
            if ((lane & 1) == 0)
                p0[(size_t)i * 32 + (lane >> 1)] = pk(pv, pn);
            m = fmaxf(m, pv);
        }
        float mn = __shfl_xor(m, 1);
        if ((lane & 1) == 0)
            vmaxb[(size_t)v * 32 + (lane >> 1)] = pk(m, mn);
    }
}

// ---------------- gstat: X1=[p0|vmax] @ W1 -> BN1 stats ONLY (no y1 write) ----------------
#define G1_SW1 0
#define G1_SX  32768
#define G1_ST  65536
#define G1_LDS (65536 + 8192)

__global__ __launch_bounds__(512) void k_gstat(const unsigned int* __restrict__ p0,
    const unsigned int* __restrict__ vmaxb, const int* __restrict__ vidx,
    const float* __restrict__ W1,
    double* __restrict__ s1d, double* __restrict__ sq1d, int n, int ntiles)
{
    extern __shared__ char lds[];
    char* sW1 = lds + G1_SW1;
    char* sx  = lds + G1_SX;
    int t = threadIdx.x, lane = t & 63, w = t >> 6;
    int pl = lane & 15, qd = lane >> 4;

    // stage W1 (128x128 f32, [k][c]) -> sW1[c][k] bf16, stride 256B, XOR swizzle
#pragma unroll
    for (int it = 0; it < 8; ++it) {
        int e = (it * 512 + t) * 4;
        float4 wv = *(const float4*)(W1 + e);
        int k = e >> 7, c0 = e & 127;
        float wa[4] = {wv.x, wv.y, wv.z, wv.w};
#pragma unroll
        for (int qq = 0; qq < 4; ++qq) {
            int c = c0 + qq;
            *(short*)(sW1 + c * 256 + ((k * 2) ^ ((c & 7) << 4))) = f2bf(wa[qq]);
        }
    }
    __syncthreads();

    float st_s[8][4], st_q[8][4];
#pragma unroll
    for (int cb = 0; cb < 8; ++cb)
#pragma unroll
        for (int jj = 0; jj < 4; ++jj) { st_s[cb][jj] = 0.f; st_q[cb][jj] = 0.f; }

    unsigned int szr = (unsigned int)(pl & 7) << 4;
    int rb_ = w * 16 + pl;
    for (int tile = blockIdx.x; tile < ntiles; tile += gridDim.x) {
        int base = tile * 128;
        {
            int p = t >> 2, s = t & 3;
            int i = base + p;
            char* rowp = sx + p * 256;
            unsigned int sz = (unsigned int)(p & 7) << 4;
            uint4 d0, d1, d2, d3;
            if (i < n) {
                const uint4* src = (s < 2)
                    ? (const uint4*)(p0 + (size_t)i * 32 + s * 16)
                    : (const uint4*)(vmaxb + (size_t)vidx[i] * 32 + (s - 2) * 16);
                d0 = src[0]; d1 = src[1]; d2 = src[2]; d3 = src[3];
            } else {
                d0 = d1 = d2 = d3 = make_uint4(0u, 0u, 0u, 0u);
            }
            int k2 = s * 64;
            *(uint4*)(rowp + ((k2 +  0) ^ sz)) = d0;
            *(uint4*)(rowp + ((k2 + 16) ^ sz)) = d1;
            *(uint4*)(rowp + ((k2 + 32) ^ sz)) = d2;
            *(uint4*)(rowp + ((k2 + 48) ^ sz)) = d3;
        }
        __syncthreads();
        // MFMA: D[row=channel][col=point]  (a=W-frag, b=x-frag)
        f32x4 acc[8];
#pragma unroll
        for (int cb = 0; cb < 8; ++cb) acc[cb] = (f32x4){0.f, 0.f, 0.f, 0.f};
#pragma unroll
        for (int kc = 0; kc < 4; ++kc) {
            int ko2 = kc * 64 + qd * 16;
            bf16x8 b = *(bf16x8*)(sx + rb_ * 256 + (ko2 ^ szr));
#pragma unroll
            for (int cb = 0; cb < 8; ++cb) {
                int ra_ = cb * 16 + pl;
                bf16x8 a = *(bf16x8*)(sW1 + ra_ * 256 + (ko2 ^ szr));
                acc[cb] = __builtin_amdgcn_mfma_f32_16x16x32_bf16(a, b, acc[cb], 0, 0, 0);
            }
        }
        int pt = base + rb_;
        if (pt < n) {
#pragma unroll
            for (int cb = 0; cb < 8; ++cb)
#pragma unroll
                for (int jj = 0; jj < 4; ++jj) {
                    float av = acc[cb][jj];
                    st_s[cb][jj] += av;
                    st_q[cb][jj] = fmaf(av, av, st_q[cb][jj]);
                }
        }
        __syncthreads();
    }
    // ---- stats reduction ----
    float* ssum = (float*)(lds + G1_ST);        // [8][128]
    float* ssq  = ssum + 8 * 128;
#pragma unroll
    for (int cb = 0; cb < 8; ++cb)
#pragma unroll
        for (int jj = 0; jj < 4; ++jj) {
            float sv = st_s[cb][jj], qv = st_q[cb][jj];
            sv += __shfl_xor(sv, 1); qv += __shfl_xor(qv, 1);
            sv += __shfl_xor(sv, 2); qv += __shfl_xor(qv, 2);
            sv += __shfl_xor(sv, 4); qv += __shfl_xor(qv, 4);
            sv += __shfl_xor(sv, 8); qv += __shfl_xor(qv, 8);
            if (pl == 0) {
                int ch = cb * 16 + qd * 4 + jj;
                ssum[w * 128 + ch] = sv;
                ssq[w * 128 + ch] = qv;
            }
        }
    __syncthreads();
    if (t < 128) {
        float s = 0.f, q = 0.f;
#pragma unroll
        for (int ww = 0; ww < 8; ++ww) { s += ssum[ww * 128 + t]; q += ssq[ww * 128 + t]; }
        atomicAdd(&s1d[t], (double)s);
        atomicAdd(&sq1d[t], (double)q);
    }
}

__global__ void k_fin1s(const double* __restrict__ s1d, const double* __restrict__ sq1d,
                        const float* __restrict__ g1, const float* __restrict__ b1,
                        float* __restrict__ sc1, float* __restrict__ sh1, int n)
{
    int c = threadIdx.x;
    double mean = s1d[c] / (double)n;
    double var = sq1d[c] / (double)n - mean * mean;
    float scale = g1[c] * rsqrtf((float)var + EPSF);
    sc1[c] = scale;
    sh1[c] = b1[c] - (float)mean * scale;
}

// ---------------- fused3: X1@W1 -> BN+ReLU (reg) -> [.|fsp]@Ws + bs -> ReLU -> out ----------------
#define F3_SW1 0
#define F3_SWS 32768
#define F3_SX  (32768 + 49152)
#define F3_SCL (32768 + 49152 + 49152)
#define F3_LDS (F3_SCL + 1536)

__global__ __launch_bounds__(512) void k_fused3(const unsigned int* __restrict__ p0,
    const unsigned int* __restrict__ vmaxb, const int* __restrict__ vidx,
    const unsigned int* __restrict__ fspc,
    const float* __restrict__ W1, const float* __restrict__ Wsp, const float* __restrict__ bsp,
    const float* __restrict__ sc1, const float* __restrict__ sh1,
    float* __restrict__ out, int n, int ntiles)
{
    extern __shared__ char lds[];
    char* sW1 = lds + F3_SW1;   // [c][k] bf16, stride 256
    char* sWs = lds + F3_SWS;   // [c][k] bf16, stride 384
    char* sx  = lds + F3_SX;    // [pt][k] bf16, stride 384 (X1 then x2)
    float* ssc = (float*)(lds + F3_SCL);
    float* ssh = ssc + 128;
    float* sbs = ssh + 128;
    int t = threadIdx.x, lane = t & 63, w = t >> 6;
    int pl = lane & 15, qd = lane >> 4;

    // stage W1 (128x128 f32 [k][c]) -> sW1[c][k] bf16, swizzled
#pragma unroll
    for (int it = 0; it < 8; ++it) {
        int e = (it * 512 + t) * 4;
        float4 wv = *(const float4*)(W1 + e);
        int k = e >> 7, c0 = e & 127;
        float wa[4] = {wv.x, wv.y, wv.z, wv.w};
#pragma unroll
        for (int qq = 0; qq < 4; ++qq) {
            int c = c0 + qq;
            *(short*)(sW1 + c * 256 + ((k * 2) ^ ((c & 7) << 4))) = f2bf(wa[qq]);
        }
    }
    // stage Ws (130x128 f32 [k][c]) -> sWs[c][k] bf16, stride 384, swizzled
    for (int it = 0; it < 9; ++it) {
        int e = (it * 512 + t) * 4;
        if (e < 16640) {
            float4 wv = *(const float4*)(Wsp + e);
            int k = e >> 7, c0 = e & 127;
            float wa[4] = {wv.x, wv.y, wv.z, wv.w};
#pragma unroll
            for (int qq = 0; qq < 4; ++qq) {
                int c = c0 + qq;
                *(short*)(sWs + c * 384 + ((k * 2) ^ ((c & 7) << 4))) = f2bf(wa[qq]);
            }
        }
    }
    // zero-pad k-bytes [260,320) for sWs and sx (128 rows each)
    for (int e = t; e < 128 * 15; e += 512) {
        int r = e / 15, qq = e - r * 15;
        int k2 = 260 + 4 * qq;
        *(unsigned int*)(sWs + r * 384 + (k2 ^ ((r & 7) << 4))) = 0u;
        *(unsigned int*)(sx  + r * 384 + (k2 ^ ((r & 7) << 4))) = 0u;
    }
    if (t < 128) { ssc[t] = sc1[t]; ssh[t] = sh1[t]; sbs[t] = bsp[t]; }
    __syncthreads();

    unsigned int szr = (unsigned int)(pl & 7) << 4;
    int rb_ = w * 16 + pl;   // this lane's point-row (owned by wave w)
    for (int tile = blockIdx.x; tile < ntiles; tile += gridDim.x) {
        int base = tile * 128;
        // ---- stage X1 tile ----
        {
            int p = t >> 2, s = t & 3;
            int i = base + p;
            char* rowp = sx + p * 384;
            unsigned int sz = (unsigned int)(p & 7) << 4;
            uint4 d0, d1, d2, d3;
            if (i < n) {
                const uint4* src = (s < 2)
                    ? (const uint4*)(p0 + (size_t)i * 32 + s * 16)
                    : (const uint4*)(vmaxb + (size_t)vidx[i] * 32 + (s - 2) * 16);
                d0 = src[0]; d1 = src[1]; d2 = src[2]; d3 = src[3];
            } else {
                d0 = d1 = d2 = d3 = make_uint4(0u, 0u, 0u, 0u);
            }
            int k2 = s * 64;
            *(uint4*)(rowp + ((k2 +  0) ^ sz)) = d0;
            *(uint4*)(rowp + ((k2 + 16) ^ sz)) = d1;
            *(uint4*)(rowp + ((k2 + 32) ^ sz)) = d2;
            *(uint4*)(rowp + ((k2 + 48) ^ sz)) = d3;
        }
        __syncthreads();
        // ---- MFMA-1: y1[ch][pt] frags ----
        f32x4 acc1[8];
#pragma unroll
        for (int cb = 0; cb < 8; ++cb) acc1[cb] = (f32x4){0.f, 0.f, 0.f, 0.f};
#pragma unroll
        for (int kc = 0; kc < 4; ++kc) {
            int ko2 = kc * 64 + qd * 16;
            bf16x8 b = *(bf16x8*)(sx + rb_ * 384 + (ko2 ^ szr));
#pragma unroll
            for (int cb = 0; cb < 8; ++cb) {
                int ra_ = cb * 16 + pl;
                bf16x8 a = *(bf16x8*)(sW1 + ra_ * 256 + (ko2 ^ szr));
                acc1[cb] = __builtin_amdgcn_mfma_f32_16x16x32_bf16(a, b, acc1[cb], 0, 0, 0);
            }
        }
        // ---- BN+ReLU in regs -> x2 into own row (no cross-wave barrier needed) ----
#pragma unroll
        for (int cb = 0; cb < 8; ++cb) {
            int ch0 = cb * 16 + qd * 4;
            float v0 = fmaxf(fmaf(acc1[cb][0], ssc[ch0 + 0], ssh[ch0 + 0]), 0.f);
            float v1 = fmaxf(fmaf(acc1[cb][1], ssc[ch0 + 1], ssh[ch0 + 1]), 0.f);
            float v2 = fmaxf(fmaf(acc1[cb][2], ssc[ch0 + 2], ssh[ch0 + 2]), 0.f);
            float v3 = fmaxf(fmaf(acc1[cb][3], ssc[ch0 + 3], ssh[ch0 + 3]), 0.f);
            u32x2 o;
            o.x = pk(v0, v1);
            o.y = pk(v2, v3);
            *(u32x2*)(sx + rb_ * 384 + ((unsigned int)(cb * 32 + qd * 8) ^ szr)) = o;
        }
        if (qd == 0) { // fsp (ch 128,129) for own row
            int i = base + rb_; if (i >= n) i = n - 1;
            unsigned int fs = fspc[i];
            *(unsigned int*)(sx + rb_ * 384 + (256u ^ szr)) = fs;
        }
        // ---- MFMA-2: out frags ----
        f32x4 acc2[8];
#pragma unroll
        for (int cb = 0; cb < 8; ++cb) acc2[cb] = (f32x4){0.f, 0.f, 0.f, 0.f};
#pragma unroll
        for (int kc = 0; kc < 5; ++kc) {
            int ko2 = kc * 64 + qd * 16;
            bf16x8 b = *(bf16x8*)(sx + rb_ * 384 + (ko2 ^ szr));
#pragma unroll
            for (int cb = 0; cb < 8; ++cb) {
                int ra_ = cb * 16 + pl;
                bf16x8 a = *(bf16x8*)(sWs + ra_ * 384 + (ko2 ^ szr));
                acc2[cb] = __builtin_amdgcn_mfma_f32_16x16x32_bf16(a, b, acc2[cb], 0, 0, 0);
            }
        }
        int pt = base + rb_;
        if (pt < n) {
            float* orow = out + (size_t)pt * 128 + qd * 4;
#pragma unroll
            for (int cb = 0; cb < 8; ++cb) {
                float4 bb = *(float4*)(sbs + cb * 16 + qd * 4);
                f32x4 o;
                o[0] = fmaxf(acc2[cb][0] + bb.x, 0.f);
                o[1] = fmaxf(acc2[cb][1] + bb.y, 0.f);
                o[2] = fmaxf(acc2[cb][2] + bb.z, 0.f);
                o[3] = fmaxf(acc2[cb][3] + bb.w, 0.f);
                __builtin_nontemporal_store(o, (f32x4*)(orow + cb * 16));
            }
        }
        __syncthreads();
    }
}

extern "C" void kernel_launch(void* const* d_in, const int* in_sizes, int n_in,
                              void* d_out, int out_size, void* d_ws, size_t ws_size,
                              hipStream_t stream)
{
    const float* feat = (const float*)d_in[0];
    const int*   coor = (const int*)d_in[1];
    const float* W0   = (const float*)d_in[2];
    const float* g0   = (const float*)d_in[3];
    const float* b0   = (const float*)d_in[4];
    const float* W1   = (const float*)d_in[5];
    const float* g1   = (const float*)d_in[6];
    const float* b1   = (const float*)d_in[7];
    const float* Wsp  = (const float*)d_in[8];
    const float* bsp  = (const float*)d_in[9];
    float* outp = (float*)d_out;

    int n = in_sizes[0] / 4;
    size_t npad = ((size_t)n + 127) & ~127ULL;

    char* ws = (char*)d_ws;
    size_t off = 0;
    auto alloc = [&](size_t bytes) { char* p = ws + off; off = (off + bytes + 255) & ~255ULL; return p; };
    int*          vidx   = (int*)alloc(npad * 4);
    // ---- contiguous zero-init region: counts | md0+s1d+sq1d ----
    float*        counts = (float*)alloc((size_t)CANVASv * 4);
    double*       md0    = (double*)alloc(105 * 8 + 256 * 8);
    double*       s1d    = (double*)((char*)md0 + 105 * 8);
    double*       sq1d   = s1d + 128;
    // ---- rest ----
    float4*       vstat  = (float4*)alloc((size_t)CANVASv * 16);
    unsigned int* x      = (unsigned int*)alloc(npad * 32);
    unsigned int* fspc   = (unsigned int*)alloc(npad * 4);
    unsigned int* p0     = (unsigned int*)alloc(npad * 128);
    unsigned int* vmaxb  = (unsigned int*)alloc((size_t)CANVASv * 128);
    int*          starts = (int*)alloc((size_t)CANVASv * 4);
    int*          perm   = (int*)alloc(npad * 4);
    int*          bsum   = (int*)alloc(1024 * 4);
    float*        sc0    = (float*)alloc(64 * 4);
    float*        sh0    = (float*)alloc(64 * 4);
    float*        sc1    = (float*)alloc(128 * 4);
    float*        sh1    = (float*)alloc(128 * 4);
    if (off > ws_size) return;

    // single merged memset: counts + md0/s1d/sq1d
    hipMemsetAsync(counts, 0, (size_t)CANVASv * 4 + 105 * 8 + 256 * 8, stream);

    int blocksN = (n + 255) / 256;
    k_scatter1<<<blocksN, 256, 0, stream>>>((const int4*)coor, vidx, counts, n);

    // counting sort by voxel
    k_scanA<<<CANVASv / 1024, 1024, 0, stream>>>(counts, starts, bsum);
    k_scanBC<<<CANVASv / 1024, 1024, 0, stream>>>(bsum, starts);
    k_perm<<<blocksN, 256, 0, stream>>>(vidx, starts, perm, n);

    // per-voxel mean + mean-dist (segmented, no atomics)
    k_seg<<<1024, 256, 0, stream>>>((const float4*)feat, starts, perm, vstat, CANVASv);

    // build x + moments
    k_prexm<<<512, 256, 0, stream>>>((const float4*)feat, (const int4*)coor, vidx, counts, vstat, x, fspc, md0, n);
    k_fin0<<<1, 64, 0, stream>>>(md0, W0, g0, b0, sc0, sh0, n);

    // per-voxel max + per-point p0 (persistent waves)
    k_vmaxv<<<2048, 256, 0, stream>>>(x, W0, sc0, sh0, starts, perm, p0, vmaxb, CANVASv);

    int ntiles = (n + 127) / 128;
    // BN1 stats (no y1 materialization)
    hipFuncSetAttribute((const void*)k_gstat, hipFuncAttributeMaxDynamicSharedMemorySize, G1_LDS);
    k_gstat<<<512, 512, G1_LDS, stream>>>(p0, vmaxb, vidx, W1, s1d, sq1d, n, ntiles);
    k_fin1s<<<1, 128, 0, stream>>>(s1d, sq1d, g1, b1, sc1, sh1, n);

    // fused layer1+BN+ReLU+layer2 -> out
    hipFuncSetAttribute((const void*)k_fused3, hipFuncAttributeMaxDynamicSharedMemorySize, F3_LDS);
    k_fused3<<<256, 512, F3_LDS, stream>>>(p0, vmaxb, vidx, fspc, W1, Wsp, bsp, sc1, sh1, outp, n, ntiles);
}